// Round 10
// baseline (582.010 us; speedup 1.0000x reference)
//
#include <hip/hip_runtime.h>
#include <hip/hip_bf16.h>
#include <math.h>
#include <stdint.h>

#define NN 10000
#define EE 100000
#define DD 768
#define HH 4
#define CC 192
#define EDIM 16
#define NREL 10
#define MP 10240           // NN padded to multiple of 256 for 256x256 GEMM tiles
#define NQ2 3200           // qkvs row stride: [q|kv-interleaved|skip|Qe(64)|pad(64)]
#define NB 3136            // Wt3 rows per layer: 3072 main (12 tiles) + 64 Qe
#define SCALE 0.07216878364870322f   // 1/sqrt(192)

using short8  = __attribute__((ext_vector_type(8))) short;
using floatx4 = __attribute__((ext_vector_type(4))) float;

// ---------------- helpers ----------------

__device__ __forceinline__ float b2f(short u) {
    union { unsigned int i; float f; } t;
    t.i = ((unsigned int)(unsigned short)u) << 16;
    return t.f;
}

__device__ __forceinline__ short f2b(float f) {
    __hip_bfloat16 h = __float2bfloat16(f);
    short r;
    __builtin_memcpy(&r, &h, 2);
    return r;
}

__device__ __forceinline__ __hip_bfloat16 rd_any(const void* p, long long j, int bf) {
    if (bf) return ((const __hip_bfloat16*)p)[j];
    return __float2bfloat16(((const float*)p)[j]);
}

// inline bf16-input detection (identical ballot heuristic as old detect_zero);
// wave-uniform, every wave computes the same value. (verified passing in R8)
__device__ __forceinline__ int detect_bf(const void* ea) {
    const unsigned short* p = (const unsigned short*)ea;
    int lane = threadIdx.x & 63;
    int nz = (p[4 * lane] != 0) ? 1 : 0;
    unsigned long long m = __ballot(nz);
    return (__popcll(m) > 8) ? 1 : 0;
}

// async global->LDS, 16B per lane; LDS dest must be wave-uniform base + lane*16
__device__ __forceinline__ void gload16(const __hip_bfloat16* g, __hip_bfloat16* l) {
    __builtin_amdgcn_global_load_lds(
        (const __attribute__((address_space(1))) unsigned int*)g,
        (__attribute__((address_space(3))) unsigned int*)l, 16, 0, 0);
}

// ---------------- input conversion (also zeroes counts/accum/done) -----------

__global__ __launch_bounds__(256) void cvt_big(
    const void* x, const void* We, const void* ea,
    __hip_bfloat16* hb, __hip_bfloat16* Web,
    int* counts, float* accum, int* done) {
    long long i = (long long)blockIdx.x * 256 + threadIdx.x;
    int bf = detect_bf(ea);
    if (i < NN) counts[i] = 0;
    if (i < DD) accum[(int)i] = 0.0f;
    if (i == 0) *done = 0;
    const long long NX = (long long)NN * DD;
    const long long NE2 = 3LL * EDIM * DD;
    if (i < NX) { hb[i] = rd_any(x, i, bf); return; } i -= NX;
    if (i < NE2) { Web[i] = rd_any(We, i, bf); return; } i -= NE2;
    if (i < (long long)(MP - NN) * DD) hb[(long long)NN * DD + i] = __float2bfloat16(0.0f);
}

// small conversions + edge count histogram (counts zeroed by preceding cvt_big;
// same stream -> ordered).
__global__ __launch_bounds__(256) void cvt_small(
    const void* ea, const void* rel, const void* Wed, const void* bed,
    const void* bk, const void* bq, const void* bv, const void* bs,
    const void* lg, const void* lb, const int* ei,
    __hip_bfloat16* eab, __hip_bfloat16* relb, __hip_bfloat16* Wedb,
    __hip_bfloat16* bedb, __hip_bfloat16* ballb, __hip_bfloat16* lgb,
    __hip_bfloat16* lbb, int* counts) {
    long long i = (long long)blockIdx.x * 256 + threadIdx.x;
    int bf = detect_bf(ea);
    if (i < 2LL * EE) { eab[i] = rd_any(ea, i, bf); return; } i -= 2LL * EE;
    if (i < NREL * (EDIM - 1)) { relb[i] = rd_any(rel, i, bf); return; } i -= NREL * (EDIM - 1);
    if (i < EDIM * EDIM) { Wedb[i] = rd_any(Wed, i, bf); return; } i -= EDIM * EDIM;
    if (i < EDIM) { bedb[i] = rd_any(bed, i, bf); return; } i -= EDIM;
    if (i < 3 * NB) {
        int l = (int)(i / NB), c = (int)(i % NB);
        const void* src; long long off; int outc;
        if (c < 768)       { src = bq; off = (long long)l * DD + c; outc = c; }
        else if (c < 1536) { int xx = c - 768;  src = bk;
                             off = (long long)l * DD + xx;
                             outc = 768 + (xx / 6) * 12 + xx % 6; }
        else if (c < 2304) { int xx = c - 1536; src = bv;
                             off = (long long)l * DD + xx;
                             outc = 768 + (xx / 6) * 12 + 6 + xx % 6; }
        else if (c < 3072) { src = bs; off = (long long)l * DD + (c - 2304); outc = c; }
        else { ballb[l * NB + c] = __float2bfloat16(0.0f); return; }  // Qe bias by wt_mq
        ballb[l * NB + outc] = rd_any(src, off, bf); return;
    } i -= 3 * NB;
    if (i < DD) { lgb[i] = rd_any(lg, i, bf); return; } i -= DD;
    if (i < DD) { lbb[i] = rd_any(lb, i, bf); return; } i -= DD;
    if (i < EE) atomicAdd(&counts[ei[EE + i]], 1);
}

// fused weight prep: grid (576, 13).
//  y<12 : transposed weights Wt3[l][n][k]; row order: q 0..767, K/V INTERLEAVED
//         768..2303 (group g: k at 768+12g, v at 768+12g+6), skip 2304..3071.
//  y==12, x<144 : Qe rows 3072+ (mq): x -> (kb = x%12, lh = x/12).
__global__ __launch_bounds__(256) void wt_mq(
    const void* Wq, const void* Wk, const void* Wv, const void* Ws,
    const void* bq, const void* ea,
    const __hip_bfloat16* __restrict__ Web, __hip_bfloat16* __restrict__ Wt3,
    __hip_bfloat16* __restrict__ ballb) {
    const int bf = detect_bf(ea);
    const int t = threadIdx.x;
    if (blockIdx.y < 12) {
        __shared__ __hip_bfloat16 tile[32][33];
        int mm = blockIdx.y;            // l*4 + m
        int l = mm >> 2, m = mm & 3;
        const void* src = (m == 0) ? Wq : (m == 1) ? Wk : (m == 2) ? Wv : Ws;
        int bx = blockIdx.x;            // 24*24 tiles of 32x32
        int tr = bx / 24, tc = bx % 24;
        int k0 = tr * 32, c0 = tc * 32;
        int rr = t >> 5, cc = t & 31;
        long long base = (long long)l * DD * DD;
#pragma unroll
        for (int p = 0; p < 4; p++)
            tile[p * 8 + rr][cc] =
                rd_any(src, base + (long long)(k0 + p * 8 + rr) * DD + c0 + cc, bf);
        __syncthreads();
        __hip_bfloat16* base_l = Wt3 + (size_t)l * NB * DD;
#pragma unroll
        for (int p = 0; p < 4; p++) {
            int xcol = c0 + p * 8 + rr;
            int row;
            if (m == 1)      row = 768 + (xcol / 6) * 12 + xcol % 6;
            else if (m == 2) row = 768 + (xcol / 6) * 12 + 6 + xcol % 6;
            else             row = m * 768 + xcol;   // m=0 -> q, m=3 -> skip(2304+)
            base_l[(size_t)row * DD + k0 + cc] = tile[cc][p * 8 + rr];
        }
        return;
    }
    // ---- mq path ----
    if (blockIdx.x >= 144) return;
    __shared__ float WeS[16][193];
    const int kb = blockIdx.x % 12, lh = blockIdx.x / 12;
    const int l = lh >> 2, hh = lh & 3;
    for (int i = t; i < 16 * 192; i += 256) {
        int j = i / 192, c = i % 192;
        WeS[j][c] = (float)Web[(size_t)l * EDIM * DD + (size_t)j * DD + hh * CC + c];
    }
    __syncthreads();
    const int k = kb * 64 + (t >> 2);
    const int j0 = (t & 3) * 4;
    float s0 = 0.f, s1 = 0.f, s2 = 0.f, s3 = 0.f;
    if (bf) {
        const short8* qp = (const short8*)((const __hip_bfloat16*)Wq +
            ((size_t)l * DD + k) * DD + hh * CC);
#pragma unroll 4
        for (int ch = 0; ch < 24; ch++) {
            short8 v = qp[ch];
#pragma unroll
            for (int u = 0; u < 8; u++) {
                float w = b2f(v[u]);
                int c = ch * 8 + u;
                s0 += w * WeS[j0 + 0][c]; s1 += w * WeS[j0 + 1][c];
                s2 += w * WeS[j0 + 2][c]; s3 += w * WeS[j0 + 3][c];
            }
        }
    } else {
        const float4* qp = (const float4*)((const float*)Wq +
            ((size_t)l * DD + k) * DD + hh * CC);
#pragma unroll 4
        for (int ch = 0; ch < 48; ch++) {
            float4 v = qp[ch];
            float wv[4] = {v.x, v.y, v.z, v.w};
#pragma unroll
            for (int u = 0; u < 4; u++) {
                float w = wv[u];
                int c = ch * 4 + u;
                s0 += w * WeS[j0 + 0][c]; s1 += w * WeS[j0 + 1][c];
                s2 += w * WeS[j0 + 2][c]; s3 += w * WeS[j0 + 3][c];
            }
        }
    }
    const size_t base = (size_t)l * NB * DD;
    const int row = 3072 + hh * 16 + j0;
    Wt3[base + (size_t)(row + 0) * DD + k] = __float2bfloat16(s0);
    Wt3[base + (size_t)(row + 1) * DD + k] = __float2bfloat16(s1);
    Wt3[base + (size_t)(row + 2) * DD + k] = __float2bfloat16(s2);
    Wt3[base + (size_t)(row + 3) * DD + k] = __float2bfloat16(s3);
    if (kb == 0 && t < 4) {
        float b0 = 0.f, b1 = 0.f, b2 = 0.f, b3 = 0.f;
        for (int c = 0; c < CC; c++) {
            float w = (float)rd_any(bq, (long long)l * DD + hh * CC + c, bf);
            b0 += w * WeS[j0 + 0][c]; b1 += w * WeS[j0 + 1][c];
            b2 += w * WeS[j0 + 2][c]; b3 += w * WeS[j0 + 3][c];
        }
        ballb[l * NB + 3072 + hh * 16 + j0 + 0] = __float2bfloat16(b0);
        ballb[l * NB + 3072 + hh * 16 + j0 + 1] = __float2bfloat16(b1);
        ballb[l * NB + 3072 + hh * 16 + j0 + 2] = __float2bfloat16(b2);
        ballb[l * NB + 3072 + hh * 16 + j0 + 3] = __float2bfloat16(b3);
    }
}

// ---------------- CSR build ----------------

// coalesced LDS scan: exclusive prefix into rowptr/cursor.
__global__ __launch_bounds__(256) void scan_kernel(const int* counts, int* rowptr,
                                                   int* cursor) {
    __shared__ int buf[NN];
    __shared__ int sdata[256];
    int t = threadIdx.x;
    for (int j = t; j < NN; j += 256) buf[j] = counts[j];
    __syncthreads();
    int base = t * 40;
    int cnt = (base < NN) ? min(40, NN - base) : 0;
    int s = 0;
    for (int i = 0; i < cnt; i++) s += buf[base + i];
    sdata[t] = s;
    __syncthreads();
    for (int off = 1; off < 256; off <<= 1) {
        int add = (t >= off) ? sdata[t - off] : 0;
        __syncthreads();
        sdata[t] += add;
        __syncthreads();
    }
    int run = sdata[t] - s;  // exclusive prefix of this chunk
    for (int i = 0; i < cnt; i++) {
        int tmp = buf[base + i];
        buf[base + i] = run;   // exclusive prefix per node
        run += tmp;
    }
    __syncthreads();
    for (int j = t; j < NN; j += 256) {
        int v = buf[j];
        cursor[j] = v;
        rowptr[j] = v;
    }
    if (t == 0) rowptr[NN] = EE;
}

// fill CSR slots AND compute edge features in one pass (weights in LDS).
// (verified passing in R8)
__global__ __launch_bounds__(256) void fill_ef(
    const int* __restrict__ ei, int* __restrict__ cursor, int* __restrict__ esrc,
    const __hip_bfloat16* __restrict__ eab, const __hip_bfloat16* __restrict__ relb,
    const __hip_bfloat16* __restrict__ Wedb, const __hip_bfloat16* __restrict__ bedb,
    __hip_bfloat16* __restrict__ efb) {
    __shared__ float WedS[16][17];
    __shared__ float relS[NREL][15];
    __shared__ float bedS[16];
    int t = threadIdx.x;
    if (t < 256) WedS[t >> 4][t & 15] = (float)Wedb[t];
    if (t < NREL * 15) relS[t / 15][t % 15] = (float)relb[t];
    if (t < 16) bedS[t] = (float)bedb[t];
    __syncthreads();
    int e = blockIdx.x * 256 + t;
    if (e >= EE) return;
    int d = ei[EE + e];
    int pos = atomicAdd(&cursor[d], 1);
    esrc[pos] = ei[e];
    int rid = (int)((float)eab[e * 2 + 0]);
    rid = min(max(rid, 0), NREL - 1);
    float w = (float)eab[e * 2 + 1];
    short8 o0, o1;
#pragma unroll
    for (int j = 0; j < 16; j++) {
        float s = bedS[j];
#pragma unroll
        for (int i = 0; i < 15; i++) s += relS[rid][i] * WedS[i][j];
        s += w * WedS[15][j];
        if (j < 8) o0[j] = f2b(s); else o1[j - 8] = f2b(s);
    }
    *(short8*)(efb + (size_t)pos * 16) = o0;
    *(short8*)(efb + (size_t)pos * 16 + 8) = o1;
}

// ---------------- 256x256 4-phase GEMM + fused Qe tail blocks ----------------
// blocks 0..479:  C[NN,3072] = A[MP,768] @ Wt[3072,768]^T + bias (4-phase skew)
// blocks 480..639: Qe columns (64-wide GEMM) — R5-measured ordering (Qe last).

__device__ __forceinline__ void stage_half(const __hip_bfloat16* g, int row0, int ktile,
                                           char* ldsdst, int tid) {
#pragma unroll
    for (int j = 0; j < 2; ++j) {
        int c = j * 512 + tid;          // linear 16B chunk index (1024 per half-tile)
        int row = c >> 3;
        int sch = (c & 7) ^ (row & 7);  // inverse-swizzled source chunk
        gload16(g + (size_t)(row0 + row) * DD + ktile * 64 + sch * 8,
                (__hip_bfloat16*)(ldsdst + c * 16));
    }
}

#define MF16(va, vb, cc) cc = __builtin_amdgcn_mfma_f32_16x16x32_bf16(va, vb, cc, 0, 0, 0)
#define BAR() __builtin_amdgcn_s_barrier()
#define WLG() asm volatile("s_waitcnt lgkmcnt(0)" ::: "memory")
#define WVM(N) asm volatile("s_waitcnt vmcnt(" #N ")" ::: "memory")
#define SB() __builtin_amdgcn_sched_barrier(0)
#define LDS8(off) (*(const short8*)(smem + (off)))

__global__ __launch_bounds__(512) void gemm256(
    const __hip_bfloat16* __restrict__ A, const __hip_bfloat16* __restrict__ Bt,
    const __hip_bfloat16* __restrict__ bias, __hip_bfloat16* __restrict__ C) {
    __shared__ __align__(16) char smem[131072];
    const int bid = (int)blockIdx.x;
    const int tid = threadIdx.x;
    const int wid = tid >> 6, lane = tid & 63;
    const int quad = lane >> 4, l15 = lane & 15;

    if (bid >= 480) {
        // ---- Qe path: 64x64 output tile, waves 0-3 compute, 4-7 idle ----
        const int m0q = (bid - 480) * 64;
        const __hip_bfloat16* Bq = Bt + (size_t)3072 * DD;
        const int xq0 = (quad ^ (l15 & 7)) * 16;
        const int xq1 = ((quad + 4) ^ (l15 & 7)) * 16;
        floatx4 qacc[4] = {};
        for (int kt = 0; kt < 12; ++kt) {
#pragma unroll
            for (int j = 0; j < 2; ++j) {
                int c = j * 512 + tid;
                int hf = c >> 9;             // 0:A, 1:B
                int cc = c & 511;
                int row = cc >> 3;
                int sch = (cc & 7) ^ (row & 7);
                const __hip_bfloat16* src = hf
                    ? (Bq + (size_t)row * DD + kt * 64 + sch * 8)
                    : (A + (size_t)(m0q + row) * DD + kt * 64 + sch * 8);
                gload16(src, (__hip_bfloat16*)(smem + c * 16));
            }
            asm volatile("s_waitcnt vmcnt(0)" ::: "memory");
            BAR();
            if (wid < 4) {
                short8 a0 = LDS8((wid * 16 + l15) * 128 + xq0);
                short8 a1 = LDS8((wid * 16 + l15) * 128 + xq1);
#pragma unroll
                for (int nt = 0; nt < 4; ++nt) {
                    short8 b0 = LDS8(8192 + (nt * 16 + l15) * 128 + xq0);
                    short8 b1 = LDS8(8192 + (nt * 16 + l15) * 128 + xq1);
                    MF16(a0, b0, qacc[nt]);
                    MF16(a1, b1, qacc[nt]);
                }
            }
            WLG();
            BAR();
        }
        if (wid < 4) {
#pragma unroll
            for (int nt = 0; nt < 4; ++nt) {
                float bb = (float)bias[3072 + nt * 16 + l15];
#pragma unroll
                for (int r = 0; r < 4; ++r) {
                    int row = m0q + wid * 16 + quad * 4 + r;
                    if (row < NN)
                        C[(size_t)row * NQ2 + 3072 + nt * 16 + l15] =
                            __float2bfloat16(qacc[nt][r] + bb);
                }
            }
        }
        return;
    }

    const int wm = wid >> 2, wn = wid & 3;          // 2M x 4N waves
    const int swz = (bid & 7) * 60 + (bid >> 3);    // bijective XCD swizzle (480=8*60)
    const int m0 = (swz / 12) * 256;
    const int n0 = (swz % 12) * 256;

    const int xa0 = (quad ^ (l15 & 7)) * 16;        // swizzled chunk offsets (bytes)
    const int xa1 = ((quad + 4) ^ (l15 & 7)) * 16;
    const int aRow = (wm * 128 + l15) * 128;        // A row base byte within slot
    const int bRow = 32768 + (wn * 64 + l15) * 128; // B row base byte within slot

    floatx4 acc[8][4] = {};
    short8 a[4][2], bA[2][2], bB[2][2];

    // prologue: kt0 {A0,A1,B0,B1} -> slot0, kt1 {B0,B1} -> slot1
    stage_half(A, m0, 0, smem + 0, tid);
    stage_half(A, m0 + 128, 0, smem + 16384, tid);
    stage_half(Bt, n0, 0, smem + 32768, tid);
    stage_half(Bt, n0 + 128, 0, smem + 49152, tid);
    stage_half(Bt, n0, 1, smem + 98304, tid);
    stage_half(Bt, n0 + 128, 1, smem + 114688, tid);
    WVM(4);
    BAR();

#pragma unroll 1
    for (int it = 0; it < 6; ++it) {
        const int kA = 2 * it + 1;                  // A halves of kt+1 -> slot1
        const int kB = (it < 5) ? 2 * it + 2 : 0;   // kt+2 -> slot0 (wrap = harmless)
        const int kC = (it < 5) ? 2 * it + 3 : 1;   // B halves of kt+3 -> slot1
        // ---- P_A0: slot0 north (m0-3 x all n); stage slot1.A(kA) ----
        stage_half(A, m0, kA, smem + 65536, tid);
        stage_half(A, m0 + 128, kA, smem + 81920, tid);
#pragma unroll
        for (int mt = 0; mt < 4; ++mt) {
            a[mt][0] = LDS8(aRow + mt * 2048 + xa0);
            a[mt][1] = LDS8(aRow + mt * 2048 + xa1);
        }
#pragma unroll
        for (int nt = 0; nt < 2; ++nt) {
            bA[nt][0] = LDS8(bRow + nt * 2048 + xa0);
            bA[nt][1] = LDS8(bRow + nt * 2048 + xa1);
            bB[nt][0] = LDS8(bRow + (nt + 2) * 2048 + xa0);
            bB[nt][1] = LDS8(bRow + (nt + 2) * 2048 + xa1);
        }
        SB(); BAR(); WLG(); SB();
        __builtin_amdgcn_s_setprio(1);
#pragma unroll
        for (int mt = 0; mt < 4; ++mt)
#pragma unroll
            for (int nt = 0; nt < 2; ++nt) {
                MF16(a[mt][0], bA[nt][0], acc[mt][nt]);
                MF16(a[mt][1], bA[nt][1], acc[mt][nt]);
                MF16(a[mt][0], bB[nt][0], acc[mt][nt + 2]);
                MF16(a[mt][1], bB[nt][1], acc[mt][nt + 2]);
            }
        __builtin_amdgcn_s_setprio(0);
        // ---- P_B0: slot0 south (m4-7); stage slot0.B(kB) ----
        stage_half(Bt, n0, kB, smem + 32768, tid);
        stage_half(Bt, n0 + 128, kB, smem + 49152, tid);
#pragma unroll
        for (int mt = 0; mt < 4; ++mt) {
            a[mt][0] = LDS8(aRow + (mt + 4) * 2048 + xa0);
            a[mt][1] = LDS8(aRow + (mt + 4) * 2048 + xa1);
        }
        WVM(4);                                     // slot1 {B(prev),A(kA)} complete
        SB(); BAR(); WLG(); SB();
        __builtin_amdgcn_s_setprio(1);
#pragma unroll
        for (int mt = 0; mt < 4; ++mt)
#pragma unroll
            for (int nt = 0; nt < 2; ++nt) {
                MF16(a[mt][0], bB[nt][0], acc[mt + 4][nt + 2]);
                MF16(a[mt][1], bB[nt][1], acc[mt + 4][nt + 2]);
                MF16(a[mt][0], bA[nt][0], acc[mt + 4][nt]);
                MF16(a[mt][1], bA[nt][1], acc[mt + 4][nt]);
            }
        __builtin_amdgcn_s_setprio(0);
        // ---- P_A1: slot1 north; stage slot0.A(kB) ----
        stage_half(A, m0, kB, smem + 0, tid);
        stage_half(A, m0 + 128, kB, smem + 16384, tid);
#pragma unroll
        for (int mt = 0; mt < 4; ++mt) {
            a[mt][0] = LDS8(65536 + aRow + mt * 2048 + xa0);
            a[mt][1] = LDS8(65536 + aRow + mt * 2048 + xa1);
        }
#pragma unroll
        for (int nt = 0; nt < 2; ++nt) {
            bA[nt][0] = LDS8(65536 + bRow + nt * 2048 + xa0);
            bA[nt][1] = LDS8(65536 + bRow + nt * 2048 + xa1);
            bB[nt][0] = LDS8(65536 + bRow + (nt + 2) * 2048 + xa0);
            bB[nt][1] = LDS8(65536 + bRow + (nt + 2) * 2048 + xa1);
        }
        SB(); BAR(); WLG(); SB();
        __builtin_amdgcn_s_setprio(1);
#pragma unroll
        for (int mt = 0; mt < 4; ++mt)
#pragma unroll
            for (int nt = 0; nt < 2; ++nt) {
                MF16(a[mt][0], bA[nt][0], acc[mt][nt]);
                MF16(a[mt][1], bA[nt][1], acc[mt][nt]);
                MF16(a[mt][0], bB[nt][0], acc[mt][nt + 2]);
                MF16(a[mt][1], bB[nt][1], acc[mt][nt + 2]);
            }
        __builtin_amdgcn_s_setprio(0);
        // ---- P_B1: slot1 south; stage slot1.B(kC) ----
        stage_half(Bt, n0, kC, smem + 98304, tid);
        stage_half(Bt, n0 + 128, kC, smem + 114688, tid);
#pragma unroll
        for (int mt = 0; mt < 4; ++mt) {
            a[mt][0] = LDS8(65536 + aRow + (mt + 4) * 2048 + xa0);
            a[mt][1] = LDS8(65536 + aRow + (mt + 4) * 2048 + xa1);
        }
        WVM(4);                                     // slot0 {B(kB),A(kB)} complete
        SB(); BAR(); WLG(); SB();
        __builtin_amdgcn_s_setprio(1);
#pragma unroll
        for (int mt = 0; mt < 4; ++mt)
#pragma unroll
            for (int nt = 0; nt < 2; ++nt) {
                MF16(a[mt][0], bB[nt][0], acc[mt + 4][nt + 2]);
                MF16(a[mt][1], bB[nt][1], acc[mt + 4][nt + 2]);
                MF16(a[mt][0], bA[nt][0], acc[mt + 4][nt]);
                MF16(a[mt][1], bA[nt][1], acc[mt + 4][nt]);
            }
        __builtin_amdgcn_s_setprio(0);
    }

    // epilogue: drain remaining stage writes, then per-wave LDS transpose-stage
    // -> coalesced 32B/lane global writes.
    asm volatile("s_waitcnt vmcnt(0)" ::: "memory");
    BAR();
    {
        short* stg = (short*)smem + wid * 1152;   // 16x68 shorts per wave, private
        float bv[4];
#pragma unroll
        for (int nt = 0; nt < 4; ++nt)
            bv[nt] = (float)bias[n0 + wn * 64 + nt * 16 + l15];
        const int rdo = (lane >> 2) * 68 + (lane & 3) * 16;
        const int grow0 = m0 + wm * 128 + (lane >> 2);
        const int gcol = n0 + wn * 64 + (lane & 3) * 16;
#pragma unroll
        for (int mt = 0; mt < 8; ++mt) {
#pragma unroll
            for (int nt = 0; nt < 4; ++nt)
#pragma unroll
                for (int r = 0; r < 4; ++r)
                    stg[(quad * 4 + r) * 68 + nt * 16 + l15] =
                        f2b(acc[mt][nt][r] + bv[nt]);
            asm volatile("s_waitcnt lgkmcnt(0)" ::: "memory");
            short8 v0 = *(const short8*)(stg + rdo);
            short8 v1 = *(const short8*)(stg + rdo + 8);
            int grow = grow0 + mt * 16;
            if (grow < NN) {
                short8* dp = (short8*)(C + (size_t)grow * NQ2 + gcol);
                dp[0] = v0; dp[1] = v1;
            }
            asm volatile("s_waitcnt lgkmcnt(0)" ::: "memory");
        }
    }
}

// ---------------- attention ----------------
// qkvs row layout (stride 3200): [q(0) | kv-interleaved(768) | skip(2304) | Qe(3072)]
// Natural node order (LPT reorder measured -25us L2 loss in R8 - do not sort).
// Lane g = half*64+lane owns channels 6g..6g+5: K at col 768+12g, V at +6 ->
// one contiguous 24B (8-aligned) read, 3x short4. Depth-1 prefetch + defer-max.

__global__ __launch_bounds__(256) void node_attn(
    const int* __restrict__ rowptr, const int* __restrict__ esrc,
    const __hip_bfloat16* __restrict__ qkvs, const __hip_bfloat16* __restrict__ efb,
    const __hip_bfloat16* __restrict__ Wel, __hip_bfloat16* __restrict__ hb,
    int do_gelu) {
    const int wv = threadIdx.x >> 6, lane = threadIdx.x & 63;
    const int n = blockIdx.x * 2 + (wv >> 1);   // grid = 5000 blocks, exact
    const int half = wv & 1;
    const int cb = half * 384 + lane * 6;       // channel base within 768
    const int g = half * 64 + lane;             // channel group (6 ch per group)
    const int kvoff = 768 + g * 12;             // qkvs col of this lane's K/V block
    const int sj = lane & 15;
    const int hsel = lane & 32;                 // head-group base within wave
    const float qe_gate = ((lane & 16) == 0) ? 1.0f : 0.0f;
    const int s0 = rowptr[n], s1 = rowptr[n + 1];
    const short* qk = (const short*)qkvs;
    float q[6];
    {
        const short2* qp = (const short2*)(qk + (size_t)n * NQ2 + cb);
        short2 a = qp[0], b = qp[1], c = qp[2];
        q[0] = b2f(a.x) * SCALE; q[1] = b2f(a.y) * SCALE; q[2] = b2f(b.x) * SCALE;
        q[3] = b2f(b.y) * SCALE; q[4] = b2f(c.x) * SCALE; q[5] = b2f(c.y) * SCALE;
    }
    const float qe_l = b2f(qk[(size_t)n * NQ2 + 3072 + (half * 2 + (lane >> 5)) * 16 + sj])
                       * SCALE * qe_gate;
    float m = -INFINITY, lsum = 0.f, sacc = 0.f;
    float acc[6] = {};
    short4 kvA = {0,0,0,0}, kvB = {0,0,0,0}, kvC = {0,0,0,0};
    float efv = 0.f;
    if (s0 < s1) {
        const short4* kv = (const short4*)(qk + (size_t)esrc[s0] * NQ2 + kvoff);
        kvA = kv[0]; kvB = kv[1]; kvC = kv[2];
        efv = b2f(((const short*)efb)[(size_t)s0 * 16 + sj]);
    }
    for (int p = s0; p < s1; p++) {
        // prefetch edge p+1 while computing edge p
        short4 nA = kvA, nB = kvB, nC = kvC;
        float nefv = efv;
        if (p + 1 < s1) {
            const short4* kv = (const short4*)(qk + (size_t)esrc[p + 1] * NQ2 + kvoff);
            nA = kv[0]; nB = kv[1]; nC = kv[2];
            nefv = b2f(((const short*)efb)[(size_t)(p + 1) * 16 + sj]);
        }
        float part = qe_l * efv;
        part += q[0] * b2f(kvA.x) + q[1] * b2f(kvA.y) + q[2] * b2f(kvA.z);
        part += q[3] * b2f(kvA.w) + q[4] * b2f(kvB.x) + q[5] * b2f(kvB.y);
        part += __shfl_xor(part, 1); part += __shfl_xor(part, 2);
        part += __shfl_xor(part, 4); part += __shfl_xor(part, 8);
        part += __shfl_xor(part, 16);
        if (part > m + 8.0f) {            // defer-max: rare rescale
            float sc = __expf(m - part);
            m = part;
            lsum *= sc; sacc *= sc;
#pragma unroll
            for (int i = 0; i < 6; i++) acc[i] *= sc;
        }
        float w = __expf(part - m);       // bounded by e^8
        lsum += w;
        sacc += w * efv;
        acc[0] += w * b2f(kvB.z); acc[1] += w * b2f(kvB.w);
        acc[2] += w * b2f(kvC.x); acc[3] += w * b2f(kvC.y);
        acc[4] += w * b2f(kvC.z); acc[5] += w * b2f(kvC.w);
        kvA = nA; kvB = nB; kvC = nC; efv = nefv;
    }
    float inv = 1.0f / (lsum + 1e-16f);
#pragma unroll
    for (int i = 0; i < 6; i++) acc[i] *= inv;
    float sS = sacc * inv;
    // skip connection
    {
        const short2* sp = (const short2*)(qk + (size_t)n * NQ2 + 2304 + cb);
        short2 a = sp[0], b = sp[1], c = sp[2];
        acc[0] += b2f(a.x); acc[1] += b2f(a.y); acc[2] += b2f(b.x);
        acc[3] += b2f(b.y); acc[4] += b2f(c.x); acc[5] += b2f(c.y);
    }
    // + S @ We (per-head 16-dim): S[h][j] broadcast via shfl from lane hsel+j
#pragma unroll
    for (int j = 0; j < 16; j++) {
        float sv = __shfl(sS, hsel + j);
        const short2* wp = (const short2*)(Wel + (size_t)j * DD + cb);
        short2 a = wp[0], b = wp[1], c = wp[2];
        acc[0] += sv * b2f(a.x); acc[1] += sv * b2f(a.y); acc[2] += sv * b2f(b.x);
        acc[3] += sv * b2f(b.y); acc[4] += sv * b2f(c.x); acc[5] += sv * b2f(c.y);
    }
    if (do_gelu) {
#pragma unroll
        for (int i = 0; i < 6; i++)
            acc[i] = 0.5f * acc[i] * (1.0f + erff(acc[i] * 0.70710678118654752f));
    }
    short2 o0, o1, o2;
    o0.x = f2b(acc[0]); o0.y = f2b(acc[1]);
    o1.x = f2b(acc[2]); o1.y = f2b(acc[3]);
    o2.x = f2b(acc[4]); o2.y = f2b(acc[5]);
    short2* hp = (short2*)(hb + (size_t)n * DD + cb);
    hp[0] = o0; hp[1] = o1; hp[2] = o2;
}

// ---------------- LN + mean pool (atomic accumulate, last block finishes) ----
// (verified passing in R8)

__global__ __launch_bounds__(256) void ln_pool(
    const __hip_bfloat16* __restrict__ hb, const __hip_bfloat16* __restrict__ g,
    const __hip_bfloat16* __restrict__ b, float* __restrict__ accum,
    int* __restrict__ done, const void* ea, void* __restrict__ out) {
    __shared__ float sbuf[4][768];
    __shared__ int lastFlag;
    int grp = blockIdx.x, t = threadIdx.x;
    int wid = t >> 6, lane = t & 63;
    float gv[12], bv[12], acc[12];
#pragma unroll
    for (int i = 0; i < 12; i++) {
        gv[i] = (float)g[lane + i * 64];
        bv[i] = (float)b[lane + i * 64];
        acc[i] = 0.f;
    }
    for (int r = wid; r < 25; r += 4) {
        const __hip_bfloat16* row = hb + (size_t)(grp * 25 + r) * DD;
        float x[12];
        float s = 0.f, q = 0.f;
#pragma unroll
        for (int i = 0; i < 12; i++) {
            x[i] = (float)row[lane + i * 64];
            s += x[i]; q += x[i] * x[i];
        }
#pragma unroll
        for (int m = 32; m > 0; m >>= 1) {
            s += __shfl_xor(s, m); q += __shfl_xor(q, m);
        }
        float mu = s * (1.0f / 768.0f);
        float ms = q * (1.0f / 768.0f);
        float inv = 1.0f / sqrtf(ms - mu * mu + 1e-5f);
#pragma unroll
        for (int i = 0; i < 12; i++)
            acc[i] += (x[i] - mu) * inv * gv[i] + bv[i];
    }
#pragma unroll
    for (int i = 0; i < 12; i++) sbuf[wid][lane + i * 64] = acc[i];
    __syncthreads();
#pragma unroll
    for (int j = 0; j < 3; j++) {
        int col = t + j * 256;
        atomicAdd(&accum[col],
                  sbuf[0][col] + sbuf[1][col] + sbuf[2][col] + sbuf[3][col]);
    }
    __threadfence();
    if (t == 0) lastFlag = (atomicAdd(done, 1) == 399);
    __syncthreads();
    if (lastFlag) {
        int bf = detect_bf(ea);
        for (int j = t; j < DD; j += 256) {
            float s = __hip_atomic_load(&accum[j], __ATOMIC_RELAXED,
                                        __HIP_MEMORY_SCOPE_AGENT) * (1.0f / 10000.0f);
            if (bf) ((__hip_bfloat16*)out)[j] = __float2bfloat16(s);
            else ((float*)out)[j] = s;
        }
    }
}

// ---------------- launch ----------------

extern "C" void kernel_launch(void* const* d_in, const int* in_sizes, int n_in,
                              void* d_out, int out_size, void* d_ws, size_t ws_size,
                              hipStream_t stream) {
    const void* x         = d_in[0];
    const void* edge_attr = d_in[1];
    const int*  ei        = (const int*)d_in[2];
    const void* rel_emb   = d_in[3];
    const void* W_edge    = d_in[4];
    const void* b_edge    = d_in[5];
    const void* Wk        = d_in[6];
    const void* bk        = d_in[7];
    const void* Wq        = d_in[8];
    const void* bq        = d_in[9];
    const void* Wv        = d_in[10];
    const void* bv        = d_in[11];
    const void* We        = d_in[12];
    const void* Wskip     = d_in[13];
    const void* bskip     = d_in[14];
    const void* ln_g      = d_in[15];
    const void* ln_b      = d_in[16];

    char* ws = (char*)d_ws;
    // ---- workspace layout (~100.4 MB total) ----
    int*   done    = (int*)(ws + 0);
    int*   counts  = (int*)(ws + 256);          // 40,000
    int*   rowptr  = (int*)(ws + 40448);        // 40,004
    int*   cursor  = (int*)(ws + 80640);        // 40,000
    int*   esrc    = (int*)(ws + 520960);       // 400,000
    __hip_bfloat16* efb = (__hip_bfloat16*)(ws + 920960);   // 3,200,000 (CSR-ordered)
    float* accum   = (float*)(ws + 4120960);    // 3,072 (pool accumulator)
    __hip_bfloat16* eab   = (__hip_bfloat16*)(ws + 5349760);  // 400,000
    __hip_bfloat16* relb  = (__hip_bfloat16*)(ws + 5749760);  // 300
    __hip_bfloat16* Wedb  = (__hip_bfloat16*)(ws + 5750144);  // 512
    __hip_bfloat16* bedb  = (__hip_bfloat16*)(ws + 5750656);  // 32
    __hip_bfloat16* ballb = (__hip_bfloat16*)(ws + 5750784);  // 18,816 (3*NB)
    __hip_bfloat16* lngb  = (__hip_bfloat16*)(ws + 5770752);  // 1,536
    __hip_bfloat16* lnbb  = (__hip_bfloat16*)(ws + 5772288);  // 1,536
    __hip_bfloat16* Web   = (__hip_bfloat16*)(ws + 5773824);  // 73,728
    __hip_bfloat16* hb    = (__hip_bfloat16*)(ws + 5847552);  // 15,728,640 (MP*768)
    __hip_bfloat16* Wt3   = (__hip_bfloat16*)(ws + 21576192); // 14,450,688 (3*NB*768)
    __hip_bfloat16* qkvs  = (__hip_bfloat16*)(ws + 36911616); // 64,000,000 -> 100,911,616

    dim3 blk(256);

    {
        long long tot = (long long)NN * DD + 3LL * EDIM * DD + (long long)(MP - NN) * DD;
        cvt_big<<<dim3((unsigned)((tot + 255) / 256)), blk, 0, stream>>>(
            x, We, edge_attr, hb, Web, counts, accum, done);
    }
    {
        long long tot = 2LL * EE + NREL * (EDIM - 1) + EDIM * EDIM + EDIM
                        + 3LL * NB + 2LL * DD + EE;
        cvt_small<<<dim3((unsigned)((tot + 255) / 256)), blk, 0, stream>>>(
            edge_attr, rel_emb, W_edge, b_edge, bk, bq, bv, bskip, ln_g, ln_b, ei,
            eab, relb, Wedb, bedb, ballb, lngb, lnbb, counts);
    }
    wt_mq<<<dim3(576, 13), blk, 0, stream>>>(Wq, Wk, Wv, Wskip, bq, edge_attr,
                                             Web, Wt3, ballb);

    scan_kernel<<<dim3(1), blk, 0, stream>>>(counts, rowptr, cursor);
    fill_ef<<<dim3((EE + 255) / 256), blk, 0, stream>>>(
        ei, cursor, esrc, eab, relb, Wedb, bedb, efb);

    for (int l = 0; l < 3; l++) {
        const __hip_bfloat16* We_l = Web + (size_t)l * EDIM * DD;
        gemm256<<<dim3(640), dim3(512), 0, stream>>>(
            hb, Wt3 + (size_t)l * NB * DD, ballb + (size_t)l * NB, qkvs);
        node_attn<<<dim3(NN / 2), blk, 0, stream>>>(rowptr, esrc, qkvs, efb,
                                                    We_l, hb, (l < 2) ? 1 : 0);
    }

    ln_pool<<<dim3(400), blk, 0, stream>>>(hb, lngb, lnbb, accum, done,
                                           edge_attr, d_out);
}

// Round 11
// 575.429 us; speedup vs baseline: 1.0114x; 1.0114x over previous
//
#include <hip/hip_runtime.h>
#include <hip/hip_bf16.h>
#include <math.h>
#include <stdint.h>

#define NN 10000
#define EE 100000
#define DD 768
#define HH 4
#define CC 192
#define EDIM 16
#define NREL 10
#define MP 10240           // NN padded to multiple of 256 for 256x256 GEMM tiles
#define NQ2 3200           // qkvs row stride: [q|kv-interleaved|skip|Qe(64)|pad(64)]
#define NB 3136            // Wt3 rows per layer: 3072 main (12 tiles) + 64 Qe
#define SCALE 0.07216878364870322f   // 1/sqrt(192)

using short8  = __attribute__((ext_vector_type(8))) short;
using floatx4 = __attribute__((ext_vector_type(4))) float;

// ---------------- helpers ----------------

__device__ __forceinline__ float b2f(short u) {
    union { unsigned int i; float f; } t;
    t.i = ((unsigned int)(unsigned short)u) << 16;
    return t.f;
}

__device__ __forceinline__ short f2b(float f) {
    __hip_bfloat16 h = __float2bfloat16(f);
    short r;
    __builtin_memcpy(&r, &h, 2);
    return r;
}

__device__ __forceinline__ __hip_bfloat16 rd_any(const void* p, long long j, int bf) {
    if (bf) return ((const __hip_bfloat16*)p)[j];
    return __float2bfloat16(((const float*)p)[j]);
}

// async global->LDS, 16B per lane; LDS dest must be wave-uniform base + lane*16
__device__ __forceinline__ void gload16(const __hip_bfloat16* g, __hip_bfloat16* l) {
    __builtin_amdgcn_global_load_lds(
        (const __attribute__((address_space(1))) unsigned int*)g,
        (__attribute__((address_space(3))) unsigned int*)l, 16, 0, 0);
}

// ---------------- dtype detect + zero counts + zero pool accum ----------------
__global__ __launch_bounds__(256) void detect_zero(const void* edge_attr,
                                                   int* flag, int* counts,
                                                   float* accum) {
    int i = blockIdx.x * 256 + threadIdx.x;
    if (i < NN) counts[i] = 0;
    if (i < DD) accum[i] = 0.0f;
    if (blockIdx.x == 0 && threadIdx.x < 64) {
        const unsigned short* p = (const unsigned short*)edge_attr;
        int nz = (p[4 * threadIdx.x] != 0) ? 1 : 0;
        unsigned long long m = __ballot(nz);
        if (threadIdx.x == 0) *flag = (__popcll(m) > 8) ? 1 : 0;
    }
}

// ---------------- input conversion ----------------

__global__ __launch_bounds__(256) void cvt_big(
    const void* x, const void* We, const int* flag,
    __hip_bfloat16* hb, __hip_bfloat16* Web) {
    long long i = (long long)blockIdx.x * 256 + threadIdx.x;
    int bf = *flag;
    const long long NX = (long long)NN * DD;
    const long long NE2 = 3LL * EDIM * DD;
    if (i < NX) { hb[i] = rd_any(x, i, bf); return; } i -= NX;
    if (i < NE2) { Web[i] = rd_any(We, i, bf); return; } i -= NE2;
    if (i < (long long)(MP - NN) * DD) hb[(long long)NN * DD + i] = __float2bfloat16(0.0f);
}

__global__ __launch_bounds__(256) void cvt_small(
    const void* ea, const void* rel, const void* Wed, const void* bed,
    const void* bk, const void* bq, const void* bv, const void* bs,
    const void* lg, const void* lb, const int* flag,
    __hip_bfloat16* eab, __hip_bfloat16* relb, __hip_bfloat16* Wedb,
    __hip_bfloat16* bedb, __hip_bfloat16* ballb, __hip_bfloat16* lgb,
    __hip_bfloat16* lbb) {
    long long i = (long long)blockIdx.x * 256 + threadIdx.x;
    int bf = *flag;
    if (i < 2LL * EE) { eab[i] = rd_any(ea, i, bf); return; } i -= 2LL * EE;
    if (i < NREL * (EDIM - 1)) { relb[i] = rd_any(rel, i, bf); return; } i -= NREL * (EDIM - 1);
    if (i < EDIM * EDIM) { Wedb[i] = rd_any(Wed, i, bf); return; } i -= EDIM * EDIM;
    if (i < EDIM) { bedb[i] = rd_any(bed, i, bf); return; } i -= EDIM;
    if (i < 3 * NB) {
        int l = (int)(i / NB), c = (int)(i % NB);
        const void* src; long long off; int outc;
        if (c < 768)       { src = bq; off = (long long)l * DD + c; outc = c; }
        else if (c < 1536) { int xx = c - 768;  src = bk;
                             off = (long long)l * DD + xx;
                             outc = 768 + (xx / 6) * 12 + xx % 6; }
        else if (c < 2304) { int xx = c - 1536; src = bv;
                             off = (long long)l * DD + xx;
                             outc = 768 + (xx / 6) * 12 + 6 + xx % 6; }
        else if (c < 3072) { src = bs; off = (long long)l * DD + (c - 2304); outc = c; }
        else { ballb[l * NB + c] = __float2bfloat16(0.0f); return; }  // Qe bias by mq_kernel
        ballb[l * NB + outc] = rd_any(src, off, bf); return;
    } i -= 3 * NB;
    if (i < DD) { lgb[i] = rd_any(lg, i, bf); return; } i -= DD;
    if (i < DD) { lbb[i] = rd_any(lb, i, bf); return; }
}

// all-layer fused transposed weights: Wt3[l][n][k].
// Column (row-of-Wt3) order: q 0..767; K/V INTERLEAVED 768..2303
// (group g: k[6g..6g+6) at 768+12g, v[6g..6g+6) at 768+12g+6); skip 2304..3071.
__global__ __launch_bounds__(256) void wt_all(
    const void* Wq, const void* Wk, const void* Wv, const void* Ws,
    const int* flag, __hip_bfloat16* Wt3) {
    __shared__ __hip_bfloat16 tile[32][33];
    int mm = blockIdx.y;            // l*4 + m
    int l = mm >> 2, m = mm & 3;
    const void* src = (m == 0) ? Wq : (m == 1) ? Wk : (m == 2) ? Wv : Ws;
    int bx = blockIdx.x;            // 24*24 tiles of 32x32
    int tr = bx / 24, tc = bx % 24;
    int k0 = tr * 32, c0 = tc * 32;
    int t = threadIdx.x;
    int rr = t >> 5, cc = t & 31;
    int bf = *flag;
    long long base = (long long)l * DD * DD;
#pragma unroll
    for (int p = 0; p < 4; p++)
        tile[p * 8 + rr][cc] =
            rd_any(src, base + (long long)(k0 + p * 8 + rr) * DD + c0 + cc, bf);
    __syncthreads();
    __hip_bfloat16* base_l = Wt3 + (size_t)l * NB * DD;
#pragma unroll
    for (int p = 0; p < 4; p++) {
        int xcol = c0 + p * 8 + rr;
        int row;
        if (m == 1)      row = 768 + (xcol / 6) * 12 + xcol % 6;
        else if (m == 2) row = 768 + (xcol / 6) * 12 + 6 + xcol % 6;
        else             row = m * 768 + xcol;       // m=0 -> q, m=3 -> skip(2304+)
        base_l[(size_t)row * DD + k0 + cc] = tile[cc][p * 8 + rr];
    }
}

// Qe-rows of Wt3: Wt3[l][3072+hj][k] = sum_c Wq[l][k][h*CC+c]*We[l][j][h*CC+c]
__global__ __launch_bounds__(256) void mq_kernel(
    const void* Wq, const void* bq, const int* flag,
    const __hip_bfloat16* __restrict__ Web, __hip_bfloat16* __restrict__ Wt3,
    __hip_bfloat16* __restrict__ ballb) {
    __shared__ float WeS[16][193];
    const int lh = blockIdx.y, l = lh >> 2, hh = lh & 3;
    const int t = threadIdx.x;
    const int bf = *flag;
    for (int i = t; i < 16 * 192; i += 256) {
        int j = i / 192, c = i % 192;
        WeS[j][c] = (float)Web[(size_t)l * EDIM * DD + (size_t)j * DD + hh * CC + c];
    }
    __syncthreads();
    const int k = blockIdx.x * 64 + (t >> 2);
    const int j0 = (t & 3) * 4;
    float s0 = 0.f, s1 = 0.f, s2 = 0.f, s3 = 0.f;
    if (bf) {
        const short8* qp = (const short8*)((const __hip_bfloat16*)Wq +
            ((size_t)l * DD + k) * DD + hh * CC);
#pragma unroll 4
        for (int ch = 0; ch < 24; ch++) {
            short8 v = qp[ch];
#pragma unroll
            for (int u = 0; u < 8; u++) {
                float w = b2f(v[u]);
                int c = ch * 8 + u;
                s0 += w * WeS[j0 + 0][c]; s1 += w * WeS[j0 + 1][c];
                s2 += w * WeS[j0 + 2][c]; s3 += w * WeS[j0 + 3][c];
            }
        }
    } else {
        const float4* qp = (const float4*)((const float*)Wq +
            ((size_t)l * DD + k) * DD + hh * CC);
#pragma unroll 4
        for (int ch = 0; ch < 48; ch++) {
            float4 v = qp[ch];
            float wv[4] = {v.x, v.y, v.z, v.w};
#pragma unroll
            for (int u = 0; u < 4; u++) {
                float w = wv[u];
                int c = ch * 4 + u;
                s0 += w * WeS[j0 + 0][c]; s1 += w * WeS[j0 + 1][c];
                s2 += w * WeS[j0 + 2][c]; s3 += w * WeS[j0 + 3][c];
            }
        }
    }
    const size_t base = (size_t)l * NB * DD;
    const int row = 3072 + hh * 16 + j0;
    Wt3[base + (size_t)(row + 0) * DD + k] = __float2bfloat16(s0);
    Wt3[base + (size_t)(row + 1) * DD + k] = __float2bfloat16(s1);
    Wt3[base + (size_t)(row + 2) * DD + k] = __float2bfloat16(s2);
    Wt3[base + (size_t)(row + 3) * DD + k] = __float2bfloat16(s3);
    if (blockIdx.x == 0 && t < 4) {
        float b0 = 0.f, b1 = 0.f, b2 = 0.f, b3 = 0.f;
        for (int c = 0; c < CC; c++) {
            float w = (float)rd_any(bq, (long long)l * DD + hh * CC + c, bf);
            b0 += w * WeS[j0 + 0][c]; b1 += w * WeS[j0 + 1][c];
            b2 += w * WeS[j0 + 2][c]; b3 += w * WeS[j0 + 3][c];
        }
        ballb[l * NB + 3072 + hh * 16 + j0 + 0] = __float2bfloat16(b0);
        ballb[l * NB + 3072 + hh * 16 + j0 + 1] = __float2bfloat16(b1);
        ballb[l * NB + 3072 + hh * 16 + j0 + 2] = __float2bfloat16(b2);
        ballb[l * NB + 3072 + hh * 16 + j0 + 3] = __float2bfloat16(b3);
    }
}

// ---------------- CSR build (incoming edges per dst) ----------------

__global__ __launch_bounds__(256) void count_kernel(const int* ei, int* counts) {
    int e = blockIdx.x * 256 + threadIdx.x;
    if (e < EE) atomicAdd(&counts[ei[EE + e]], 1);
}

// coalesced LDS scan: exclusive prefix into rowptr/cursor.
__global__ __launch_bounds__(256) void scan_kernel(const int* counts, int* rowptr,
                                                   int* cursor) {
    __shared__ int buf[NN];
    __shared__ int sdata[256];
    int t = threadIdx.x;
    for (int j = t; j < NN; j += 256) buf[j] = counts[j];
    __syncthreads();
    int base = t * 40;
    int cnt = (base < NN) ? min(40, NN - base) : 0;
    int s = 0;
    for (int i = 0; i < cnt; i++) s += buf[base + i];
    sdata[t] = s;
    __syncthreads();
    for (int off = 1; off < 256; off <<= 1) {
        int add = (t >= off) ? sdata[t - off] : 0;
        __syncthreads();
        sdata[t] += add;
        __syncthreads();
    }
    int run = sdata[t] - s;  // exclusive prefix of this chunk
    for (int i = 0; i < cnt; i++) {
        int tmp = buf[base + i];
        buf[base + i] = run;   // exclusive prefix per node
        run += tmp;
    }
    __syncthreads();
    for (int j = t; j < NN; j += 256) {
        int v = buf[j];
        cursor[j] = v;
        rowptr[j] = v;
    }
    if (t == 0) rowptr[NN] = EE;
}

__global__ __launch_bounds__(256) void fill_kernel(const int* ei, int* cursor,
                                                   int* eids, int* esrc) {
    int e = blockIdx.x * 256 + threadIdx.x;
    if (e < EE) {
        int d = ei[EE + e];
        int pos = atomicAdd(&cursor[d], 1);
        eids[pos] = e;
        esrc[pos] = ei[e];
    }
}

// ---------------- edge features (CSR-ordered, bf16) ----------------

__global__ __launch_bounds__(256) void ef_kernel(
    const int* __restrict__ eids,
    const __hip_bfloat16* __restrict__ eab, const __hip_bfloat16* __restrict__ relb,
    const __hip_bfloat16* __restrict__ Wedb, const __hip_bfloat16* __restrict__ bedb,
    __hip_bfloat16* __restrict__ efb) {
    int idx = blockIdx.x * 256 + threadIdx.x;
    if (idx >= EE * EDIM) return;
    int p = idx >> 4, j = idx & 15;
    int e = eids[p];
    int rid = (int)((float)eab[e * 2 + 0]);
    rid = min(max(rid, 0), NREL - 1);
    float w = (float)eab[e * 2 + 1];
    float s = (float)bedb[j];
#pragma unroll
    for (int i = 0; i < 15; i++)
        s += (float)relb[rid * 15 + i] * (float)Wedb[i * EDIM + j];
    s += w * (float)Wedb[15 * EDIM + j];
    efb[idx] = __float2bfloat16(s);
}

// ---------------- 256x256 4-phase GEMM + fused Qe tail blocks ----------------
// blocks 0..479:  C[NN,3072] = A[MP,768] @ Wt[3072,768]^T + bias (4-phase skew)
// blocks 480..639: Qe columns (64-wide GEMM) — Qe LAST (measured best: R5/R10
// 65.7-66.8us vs Qe-first 68.3-69.1us).

__device__ __forceinline__ void stage_half(const __hip_bfloat16* g, int row0, int ktile,
                                           char* ldsdst, int tid) {
#pragma unroll
    for (int j = 0; j < 2; ++j) {
        int c = j * 512 + tid;          // linear 16B chunk index (1024 per half-tile)
        int row = c >> 3;
        int sch = (c & 7) ^ (row & 7);  // inverse-swizzled source chunk
        gload16(g + (size_t)(row0 + row) * DD + ktile * 64 + sch * 8,
                (__hip_bfloat16*)(ldsdst + c * 16));
    }
}

#define MF16(va, vb, cc) cc = __builtin_amdgcn_mfma_f32_16x16x32_bf16(va, vb, cc, 0, 0, 0)
#define BAR() __builtin_amdgcn_s_barrier()
#define WLG() asm volatile("s_waitcnt lgkmcnt(0)" ::: "memory")
#define WVM(N) asm volatile("s_waitcnt vmcnt(" #N ")" ::: "memory")
#define SB() __builtin_amdgcn_sched_barrier(0)
#define LDS8(off) (*(const short8*)(smem + (off)))

__global__ __launch_bounds__(512) void gemm256(
    const __hip_bfloat16* __restrict__ A, const __hip_bfloat16* __restrict__ Bt,
    const __hip_bfloat16* __restrict__ bias, __hip_bfloat16* __restrict__ C) {
    __shared__ __align__(16) char smem[131072];
    const int bid = (int)blockIdx.x;
    const int tid = threadIdx.x;
    const int wid = tid >> 6, lane = tid & 63;
    const int quad = lane >> 4, l15 = lane & 15;

    if (bid >= 480) {
        // ---- Qe path: 64x64 output tile, waves 0-3 compute, 4-7 idle ----
        const int m0q = (bid - 480) * 64;
        const __hip_bfloat16* Bq = Bt + (size_t)3072 * DD;
        const int xq0 = (quad ^ (l15 & 7)) * 16;
        const int xq1 = ((quad + 4) ^ (l15 & 7)) * 16;
        floatx4 qacc[4] = {};
        for (int kt = 0; kt < 12; ++kt) {
#pragma unroll
            for (int j = 0; j < 2; ++j) {
                int c = j * 512 + tid;
                int hf = c >> 9;             // 0:A, 1:B
                int cc = c & 511;
                int row = cc >> 3;
                int sch = (cc & 7) ^ (row & 7);
                const __hip_bfloat16* src = hf
                    ? (Bq + (size_t)row * DD + kt * 64 + sch * 8)
                    : (A + (size_t)(m0q + row) * DD + kt * 64 + sch * 8);
                gload16(src, (__hip_bfloat16*)(smem + c * 16));
            }
            asm volatile("s_waitcnt vmcnt(0)" ::: "memory");
            BAR();
            if (wid < 4) {
                short8 a0 = LDS8((wid * 16 + l15) * 128 + xq0);
                short8 a1 = LDS8((wid * 16 + l15) * 128 + xq1);
#pragma unroll
                for (int nt = 0; nt < 4; ++nt) {
                    short8 b0 = LDS8(8192 + (nt * 16 + l15) * 128 + xq0);
                    short8 b1 = LDS8(8192 + (nt * 16 + l15) * 128 + xq1);
                    MF16(a0, b0, qacc[nt]);
                    MF16(a1, b1, qacc[nt]);
                }
            }
            WLG();
            BAR();
        }
        if (wid < 4) {
#pragma unroll
            for (int nt = 0; nt < 4; ++nt) {
                float bb = (float)bias[3072 + nt * 16 + l15];
#pragma unroll
                for (int r = 0; r < 4; ++r) {
                    int row = m0q + wid * 16 + quad * 4 + r;
                    if (row < NN)
                        C[(size_t)row * NQ2 + 3072 + nt * 16 + l15] =
                            __float2bfloat16(qacc[nt][r] + bb);
                }
            }
        }
        return;
    }

    const int wm = wid >> 2, wn = wid & 3;          // 2M x 4N waves
    const int swz = (bid & 7) * 60 + (bid >> 3);    // bijective XCD swizzle (480=8*60)
    const int m0 = (swz / 12) * 256;
    const int n0 = (swz % 12) * 256;

    const int xa0 = (quad ^ (l15 & 7)) * 16;        // swizzled chunk offsets (bytes)
    const int xa1 = ((quad + 4) ^ (l15 & 7)) * 16;
    const int aRow = (wm * 128 + l15) * 128;        // A row base byte within slot
    const int bRow = 32768 + (wn * 64 + l15) * 128; // B row base byte within slot

    floatx4 acc[8][4] = {};
    short8 a[4][2], bA[2][2], bB[2][2];

    // prologue: kt0 {A0,A1,B0,B1} -> slot0, kt1 {B0,B1} -> slot1
    stage_half(A, m0, 0, smem + 0, tid);
    stage_half(A, m0 + 128, 0, smem + 16384, tid);
    stage_half(Bt, n0, 0, smem + 32768, tid);
    stage_half(Bt, n0 + 128, 0, smem + 49152, tid);
    stage_half(Bt, n0, 1, smem + 98304, tid);
    stage_half(Bt, n0 + 128, 1, smem + 114688, tid);
    WVM(4);
    BAR();

#pragma unroll 1
    for (int it = 0; it < 6; ++it) {
        const int kA = 2 * it + 1;                  // A halves of kt+1 -> slot1
        const int kB = (it < 5) ? 2 * it + 2 : 0;   // kt+2 -> slot0 (wrap = harmless)
        const int kC = (it < 5) ? 2 * it + 3 : 1;   // B halves of kt+3 -> slot1
        // ---- P_A0: slot0 north (m0-3 x all n); stage slot1.A(kA) ----
        stage_half(A, m0, kA, smem + 65536, tid);
        stage_half(A, m0 + 128, kA, smem + 81920, tid);
#pragma unroll
        for (int mt = 0; mt < 4; ++mt) {
            a[mt][0] = LDS8(aRow + mt * 2048 + xa0);
            a[mt][1] = LDS8(aRow + mt * 2048 + xa1);
        }
#pragma unroll
        for (int nt = 0; nt < 2; ++nt) {
            bA[nt][0] = LDS8(bRow + nt * 2048 + xa0);
            bA[nt][1] = LDS8(bRow + nt * 2048 + xa1);
            bB[nt][0] = LDS8(bRow + (nt + 2) * 2048 + xa0);
            bB[nt][1] = LDS8(bRow + (nt + 2) * 2048 + xa1);
        }
        SB(); BAR(); WLG(); SB();
        __builtin_amdgcn_s_setprio(1);
#pragma unroll
        for (int mt = 0; mt < 4; ++mt)
#pragma unroll
            for (int nt = 0; nt < 2; ++nt) {
                MF16(a[mt][0], bA[nt][0], acc[mt][nt]);
                MF16(a[mt][1], bA[nt][1], acc[mt][nt]);
                MF16(a[mt][0], bB[nt][0], acc[mt][nt + 2]);
                MF16(a[mt][1], bB[nt][1], acc[mt][nt + 2]);
            }
        __builtin_amdgcn_s_setprio(0);
        // ---- P_B0: slot0 south (m4-7); stage slot0.B(kB) ----
        stage_half(Bt, n0, kB, smem + 32768, tid);
        stage_half(Bt, n0 + 128, kB, smem + 49152, tid);
#pragma unroll
        for (int mt = 0; mt < 4; ++mt) {
            a[mt][0] = LDS8(aRow + (mt + 4) * 2048 + xa0);
            a[mt][1] = LDS8(aRow + (mt + 4) * 2048 + xa1);
        }
        WVM(4);                                     // slot1 {B(prev),A(kA)} complete
        SB(); BAR(); WLG(); SB();
        __builtin_amdgcn_s_setprio(1);
#pragma unroll
        for (int mt = 0; mt < 4; ++mt)
#pragma unroll
            for (int nt = 0; nt < 2; ++nt) {
                MF16(a[mt][0], bB[nt][0], acc[mt + 4][nt + 2]);
                MF16(a[mt][1], bB[nt][1], acc[mt + 4][nt + 2]);
                MF16(a[mt][0], bA[nt][0], acc[mt + 4][nt]);
                MF16(a[mt][1], bA[nt][1], acc[mt + 4][nt]);
            }
        __builtin_amdgcn_s_setprio(0);
        // ---- P_A1: slot1 north; stage slot0.A(kB) ----
        stage_half(A, m0, kB, smem + 0, tid);
        stage_half(A, m0 + 128, kB, smem + 16384, tid);
#pragma unroll
        for (int mt = 0; mt < 4; ++mt) {
            a[mt][0] = LDS8(65536 + aRow + mt * 2048 + xa0);
            a[mt][1] = LDS8(65536 + aRow + mt * 2048 + xa1);
        }
#pragma unroll
        for (int nt = 0; nt < 2; ++nt) {
            bA[nt][0] = LDS8(65536 + bRow + nt * 2048 + xa0);
            bA[nt][1] = LDS8(65536 + bRow + nt * 2048 + xa1);
            bB[nt][0] = LDS8(65536 + bRow + (nt + 2) * 2048 + xa0);
            bB[nt][1] = LDS8(65536 + bRow + (nt + 2) * 2048 + xa1);
        }
        SB(); BAR(); WLG(); SB();
        __builtin_amdgcn_s_setprio(1);
#pragma unroll
        for (int mt = 0; mt < 4; ++mt)
#pragma unroll
            for (int nt = 0; nt < 2; ++nt) {
                MF16(a[mt][0], bA[nt][0], acc[mt][nt]);
                MF16(a[mt][1], bA[nt][1], acc[mt][nt]);
                MF16(a[mt][0], bB[nt][0], acc[mt][nt + 2]);
                MF16(a[mt][1], bB[nt][1], acc[mt][nt + 2]);
            }
        __builtin_amdgcn_s_setprio(0);
        // ---- P_B1: slot1 south; stage slot1.B(kC) ----
        stage_half(Bt, n0, kC, smem + 98304, tid);
        stage_half(Bt, n0 + 128, kC, smem + 114688, tid);
#pragma unroll
        for (int mt = 0; mt < 4; ++mt) {
            a[mt][0] = LDS8(65536 + aRow + (mt + 4) * 2048 + xa0);
            a[mt][1] = LDS8(65536 + aRow + (mt + 4) * 2048 + xa1);
        }
        WVM(4);                                     // slot0 {B(kB),A(kB)} complete
        SB(); BAR(); WLG(); SB();
        __builtin_amdgcn_s_setprio(1);
#pragma unroll
        for (int mt = 0; mt < 4; ++mt)
#pragma unroll
            for (int nt = 0; nt < 2; ++nt) {
                MF16(a[mt][0], bB[nt][0], acc[mt + 4][nt + 2]);
                MF16(a[mt][1], bB[nt][1], acc[mt + 4][nt + 2]);
                MF16(a[mt][0], bA[nt][0], acc[mt + 4][nt]);
                MF16(a[mt][1], bA[nt][1], acc[mt + 4][nt]);
            }
        __builtin_amdgcn_s_setprio(0);
    }

    // epilogue: drain remaining stage writes, then per-wave LDS transpose-stage
    // -> coalesced 32B/lane global writes.
    asm volatile("s_waitcnt vmcnt(0)" ::: "memory");
    BAR();
    {
        short* stg = (short*)smem + wid * 1152;   // 16x68 shorts per wave, private
        float bv[4];
#pragma unroll
        for (int nt = 0; nt < 4; ++nt)
            bv[nt] = (float)bias[n0 + wn * 64 + nt * 16 + l15];
        const int rdo = (lane >> 2) * 68 + (lane & 3) * 16;
        const int grow0 = m0 + wm * 128 + (lane >> 2);
        const int gcol = n0 + wn * 64 + (lane & 3) * 16;
#pragma unroll
        for (int mt = 0; mt < 8; ++mt) {
#pragma unroll
            for (int nt = 0; nt < 4; ++nt)
#pragma unroll
                for (int r = 0; r < 4; ++r)
                    stg[(quad * 4 + r) * 68 + nt * 16 + l15] =
                        f2b(acc[mt][nt][r] + bv[nt]);
            asm volatile("s_waitcnt lgkmcnt(0)" ::: "memory");
            short8 v0 = *(const short8*)(stg + rdo);
            short8 v1 = *(const short8*)(stg + rdo + 8);
            int grow = grow0 + mt * 16;
            if (grow < NN) {
                short8* dp = (short8*)(C + (size_t)grow * NQ2 + gcol);
                dp[0] = v0; dp[1] = v1;
            }
            asm volatile("s_waitcnt lgkmcnt(0)" ::: "memory");
        }
    }
}

// ---------------- attention ----------------
// qkvs row layout (stride 3200): [q(0) | kv-interleaved(768) | skip(2304) | Qe(3072)]
// Natural node order (LPT reorder measured as L2-locality loss - do not sort).
// Lane g = half*64+lane owns channels 6g..6g+5: K at col 768+12g, V at +6 ->
// one contiguous 24B (8-aligned) read, 3x short4. Depth-1 prefetch + defer-max.

__global__ __launch_bounds__(256) void node_attn(
    const int* __restrict__ rowptr, const int* __restrict__ esrc,
    const __hip_bfloat16* __restrict__ qkvs, const __hip_bfloat16* __restrict__ efb,
    const __hip_bfloat16* __restrict__ Wel, __hip_bfloat16* __restrict__ hb,
    int do_gelu) {
    const int wv = threadIdx.x >> 6, lane = threadIdx.x & 63;
    const int n = blockIdx.x * 2 + (wv >> 1);   // grid = 5000 blocks, exact
    const int half = wv & 1;
    const int cb = half * 384 + lane * 6;       // channel base within 768
    const int g = half * 64 + lane;             // channel group (6 ch per group)
    const int kvoff = 768 + g * 12;             // qkvs col of this lane's K/V block
    const int sj = lane & 15;
    const int hsel = lane & 32;                 // head-group base within wave
    const float qe_gate = ((lane & 16) == 0) ? 1.0f : 0.0f;
    const int s0 = rowptr[n], s1 = rowptr[n + 1];
    const short* qk = (const short*)qkvs;
    float q[6];
    {
        const short2* qp = (const short2*)(qk + (size_t)n * NQ2 + cb);
        short2 a = qp[0], b = qp[1], c = qp[2];
        q[0] = b2f(a.x) * SCALE; q[1] = b2f(a.y) * SCALE; q[2] = b2f(b.x) * SCALE;
        q[3] = b2f(b.y) * SCALE; q[4] = b2f(c.x) * SCALE; q[5] = b2f(c.y) * SCALE;
    }
    const float qe_l = b2f(qk[(size_t)n * NQ2 + 3072 + (half * 2 + (lane >> 5)) * 16 + sj])
                       * SCALE * qe_gate;
    float m = -INFINITY, lsum = 0.f, sacc = 0.f;
    float acc[6] = {};
    short4 kvA = {0,0,0,0}, kvB = {0,0,0,0}, kvC = {0,0,0,0};
    float efv = 0.f;
    if (s0 < s1) {
        const short4* kv = (const short4*)(qk + (size_t)esrc[s0] * NQ2 + kvoff);
        kvA = kv[0]; kvB = kv[1]; kvC = kv[2];
        efv = b2f(((const short*)efb)[(size_t)s0 * 16 + sj]);
    }
    for (int p = s0; p < s1; p++) {
        // prefetch edge p+1 while computing edge p
        short4 nA = kvA, nB = kvB, nC = kvC;
        float nefv = efv;
        if (p + 1 < s1) {
            const short4* kv = (const short4*)(qk + (size_t)esrc[p + 1] * NQ2 + kvoff);
            nA = kv[0]; nB = kv[1]; nC = kv[2];
            nefv = b2f(((const short*)efb)[(size_t)(p + 1) * 16 + sj]);
        }
        float part = qe_l * efv;
        part += q[0] * b2f(kvA.x) + q[1] * b2f(kvA.y) + q[2] * b2f(kvA.z);
        part += q[3] * b2f(kvA.w) + q[4] * b2f(kvB.x) + q[5] * b2f(kvB.y);
        part += __shfl_xor(part, 1); part += __shfl_xor(part, 2);
        part += __shfl_xor(part, 4); part += __shfl_xor(part, 8);
        part += __shfl_xor(part, 16);
        if (part > m + 8.0f) {            // defer-max: rare rescale
            float sc = __expf(m - part);
            m = part;
            lsum *= sc; sacc *= sc;
#pragma unroll
            for (int i = 0; i < 6; i++) acc[i] *= sc;
        }
        float w = __expf(part - m);       // bounded by e^8
        lsum += w;
        sacc += w * efv;
        acc[0] += w * b2f(kvB.z); acc[1] += w * b2f(kvB.w);
        acc[2] += w * b2f(kvC.x); acc[3] += w * b2f(kvC.y);
        acc[4] += w * b2f(kvC.z); acc[5] += w * b2f(kvC.w);
        kvA = nA; kvB = nB; kvC = nC; efv = nefv;
    }
    float inv = 1.0f / (lsum + 1e-16f);
#pragma unroll
    for (int i = 0; i < 6; i++) acc[i] *= inv;
    float sS = sacc * inv;
    // skip connection
    {
        const short2* sp = (const short2*)(qk + (size_t)n * NQ2 + 2304 + cb);
        short2 a = sp[0], b = sp[1], c = sp[2];
        acc[0] += b2f(a.x); acc[1] += b2f(a.y); acc[2] += b2f(b.x);
        acc[3] += b2f(b.y); acc[4] += b2f(c.x); acc[5] += b2f(c.y);
    }
    // + S @ We (per-head 16-dim): S[h][j] broadcast via shfl from lane hsel+j
#pragma unroll
    for (int j = 0; j < 16; j++) {
        float sv = __shfl(sS, hsel + j);
        const short2* wp = (const short2*)(Wel + (size_t)j * DD + cb);
        short2 a = wp[0], b = wp[1], c = wp[2];
        acc[0] += sv * b2f(a.x); acc[1] += sv * b2f(a.y); acc[2] += sv * b2f(b.x);
        acc[3] += sv * b2f(b.y); acc[4] += sv * b2f(c.x); acc[5] += sv * b2f(c.y);
    }
    if (do_gelu) {
#pragma unroll
        for (int i = 0; i < 6; i++)
            acc[i] = 0.5f * acc[i] * (1.0f + erff(acc[i] * 0.70710678118654752f));
    }
    short2 o0, o1, o2;
    o0.x = f2b(acc[0]); o0.y = f2b(acc[1]);
    o1.x = f2b(acc[2]); o1.y = f2b(acc[3]);
    o2.x = f2b(acc[4]); o2.y = f2b(acc[5]);
    short2* hp = (short2*)(hb + (size_t)n * DD + cb);
    hp[0] = o0; hp[1] = o1; hp[2] = o2;
}

// ---------------- LN + mean pool (atomic accumulate) ----------------

__global__ __launch_bounds__(256) void ln_pool(
    const __hip_bfloat16* __restrict__ hb, const __hip_bfloat16* __restrict__ g,
    const __hip_bfloat16* __restrict__ b, float* __restrict__ accum) {
    __shared__ float sbuf[4][768];
    int grp = blockIdx.x, t = threadIdx.x;
    int wid = t >> 6, lane = t & 63;
    float gv[12], bv[12], acc[12];
#pragma unroll
    for (int i = 0; i < 12; i++) {
        gv[i] = (float)g[lane + i * 64];
        bv[i] = (float)b[lane + i * 64];
        acc[i] = 0.f;
    }
    for (int r = wid; r < 25; r += 4) {
        const __hip_bfloat16* row = hb + (size_t)(grp * 25 + r) * DD;
        float x[12];
        float s = 0.f, q = 0.f;
#pragma unroll
        for (int i = 0; i < 12; i++) {
            x[i] = (float)row[lane + i * 64];
            s += x[i]; q += x[i] * x[i];
        }
#pragma unroll
        for (int m = 32; m > 0; m >>= 1) {
            s += __shfl_xor(s, m); q += __shfl_xor(q, m);
        }
        float mu = s * (1.0f / 768.0f);
        float ms = q * (1.0f / 768.0f);
        float inv = 1.0f / sqrtf(ms - mu * mu + 1e-5f);
#pragma unroll
        for (int i = 0; i < 12; i++)
            acc[i] += (x[i] - mu) * inv * gv[i] + bv[i];
    }
#pragma unroll
    for (int i = 0; i < 12; i++) sbuf[wid][lane + i * 64] = acc[i];
    __syncthreads();
#pragma unroll
    for (int j = 0; j < 3; j++) {
        int col = t + j * 256;
        atomicAdd(&accum[col],
                  sbuf[0][col] + sbuf[1][col] + sbuf[2][col] + sbuf[3][col]);
    }
}

// final: scale accumulated column sums, store output
__global__ __launch_bounds__(256) void pool_final(
    const float* __restrict__ accum, void* __restrict__ out,
    const int* __restrict__ flag) {
    int dd = blockIdx.x * 256 + threadIdx.x;
    if (dd >= DD) return;
    float s = accum[dd] * (1.0f / 10000.0f);
    if (*flag) ((__hip_bfloat16*)out)[dd] = __float2bfloat16(s);
    else ((float*)out)[dd] = s;
}

// ---------------- launch ----------------

extern "C" void kernel_launch(void* const* d_in, const int* in_sizes, int n_in,
                              void* d_out, int out_size, void* d_ws, size_t ws_size,
                              hipStream_t stream) {
    const void* x         = d_in[0];
    const void* edge_attr = d_in[1];
    const int*  ei        = (const int*)d_in[2];
    const void* rel_emb   = d_in[3];
    const void* W_edge    = d_in[4];
    const void* b_edge    = d_in[5];
    const void* Wk        = d_in[6];
    const void* bk        = d_in[7];
    const void* Wq        = d_in[8];
    const void* bq        = d_in[9];
    const void* Wv        = d_in[10];
    const void* bv        = d_in[11];
    const void* We        = d_in[12];
    const void* Wskip     = d_in[13];
    const void* bskip     = d_in[14];
    const void* ln_g      = d_in[15];
    const void* ln_b      = d_in[16];

    char* ws = (char*)d_ws;
    // ---- workspace layout (~100.4 MB total) ----
    int*   flag    = (int*)(ws + 0);
    int*   counts  = (int*)(ws + 256);          // 40,000
    int*   rowptr  = (int*)(ws + 40448);        // 40,004
    int*   cursor  = (int*)(ws + 80640);        // 40,000
    int*   eids    = (int*)(ws + 120832);       // 400,000
    int*   esrc    = (int*)(ws + 520960);       // 400,000
    __hip_bfloat16* efb = (__hip_bfloat16*)(ws + 920960);   // 3,200,000 (CSR-ordered)
    float* accum   = (float*)(ws + 4120960);    // 3,072 (pool accumulator)
    __hip_bfloat16* eab   = (__hip_bfloat16*)(ws + 5349760);  // 400,000
    __hip_bfloat16* relb  = (__hip_bfloat16*)(ws + 5749760);  // 300
    __hip_bfloat16* Wedb  = (__hip_bfloat16*)(ws + 5750144);  // 512
    __hip_bfloat16* bedb  = (__hip_bfloat16*)(ws + 5750656);  // 32
    __hip_bfloat16* ballb = (__hip_bfloat16*)(ws + 5750784);  // 18,816 (3*NB)
    __hip_bfloat16* lngb  = (__hip_bfloat16*)(ws + 5770752);  // 1,536
    __hip_bfloat16* lnbb  = (__hip_bfloat16*)(ws + 5772288);  // 1,536
    __hip_bfloat16* Web   = (__hip_bfloat16*)(ws + 5773824);  // 73,728
    __hip_bfloat16* hb    = (__hip_bfloat16*)(ws + 5847552);  // 15,728,640 (MP*768)
    __hip_bfloat16* Wt3   = (__hip_bfloat16*)(ws + 21576192); // 14,450,688 (3*NB*768)
    __hip_bfloat16* qkvs  = (__hip_bfloat16*)(ws + 36911616); // 64,000,000 -> 100,911,616

    dim3 blk(256);

    detect_zero<<<dim3(40), blk, 0, stream>>>(edge_attr, flag, counts, accum);

    {
        long long tot = (long long)NN * DD + 3LL * EDIM * DD + (long long)(MP - NN) * DD;
        cvt_big<<<dim3((unsigned)((tot + 255) / 256)), blk, 0, stream>>>(x, We, flag, hb, Web);
    }
    {
        long long tot = 2LL * EE + NREL * (EDIM - 1) + EDIM * EDIM + EDIM
                        + 3LL * NB + 2LL * DD;
        cvt_small<<<dim3((unsigned)((tot + 255) / 256)), blk, 0, stream>>>(
            edge_attr, rel_emb, W_edge, b_edge, bk, bq, bv, bskip, ln_g, ln_b,
            flag, eab, relb, Wedb, bedb, ballb, lngb, lnbb);
    }
    wt_all<<<dim3(576, 12), blk, 0, stream>>>(Wq, Wk, Wv, Wskip, flag, Wt3);
    mq_kernel<<<dim3(12, 12), blk, 0, stream>>>(Wq, bq, flag, Web, Wt3, ballb);

    // CSR build
    count_kernel<<<dim3((EE + 255) / 256), blk, 0, stream>>>(ei, counts);
    scan_kernel<<<dim3(1), blk, 0, stream>>>(counts, rowptr, cursor);
    fill_kernel<<<dim3((EE + 255) / 256), blk, 0, stream>>>(ei, cursor, eids, esrc);

    ef_kernel<<<dim3((EE * EDIM) / 256), blk, 0, stream>>>(eids, eab, relb, Wedb, bedb, efb);

    for (int l = 0; l < 3; l++) {
        const __hip_bfloat16* We_l = Web + (size_t)l * EDIM * DD;
        gemm256<<<dim3(640), dim3(512), 0, stream>>>(
            hb, Wt3 + (size_t)l * NB * DD, ballb + (size_t)l * NB, qkvs);
        node_attn<<<dim3(NN / 2), blk, 0, stream>>>(rowptr, esrc, qkvs, efb,
                                                    We_l, hb, (l < 2) ? 1 : 0);
    }

    ln_pool<<<dim3(400), blk, 0, stream>>>(hb, lngb, lnbb, accum);
    pool_final<<<dim3(3), blk, 0, stream>>>(accum, d_out, flag);
}

// Round 12
// 566.871 us; speedup vs baseline: 1.0267x; 1.0151x over previous
//
#include <hip/hip_runtime.h>
#include <hip/hip_bf16.h>
#include <math.h>
#include <stdint.h>

#define NN 10000
#define EE 100000
#define DD 768
#define HH 4
#define CC 192
#define EDIM 16
#define NREL 10
#define MP 10240           // NN padded to multiple of 256 for 256x256 GEMM tiles
#define NQ2 3200           // qkvs row stride: [q|kv-interleaved|skip|Qe(64)|pad(64)]
#define NB 3136            // Wt3 rows per layer: 3072 main (12 tiles) + 64 Qe
#define SCALE 0.07216878364870322f   // 1/sqrt(192)

using short8  = __attribute__((ext_vector_type(8))) short;
using floatx4 = __attribute__((ext_vector_type(4))) float;

// ---------------- helpers ----------------

__device__ __forceinline__ float b2f(short u) {
    union { unsigned int i; float f; } t;
    t.i = ((unsigned int)(unsigned short)u) << 16;
    return t.f;
}

__device__ __forceinline__ short f2b(float f) {
    __hip_bfloat16 h = __float2bfloat16(f);
    short r;
    __builtin_memcpy(&r, &h, 2);
    return r;
}

__device__ __forceinline__ __hip_bfloat16 rd_any(const void* p, long long j, int bf) {
    if (bf) return ((const __hip_bfloat16*)p)[j];
    return __float2bfloat16(((const float*)p)[j]);
}

// async global->LDS, 16B per lane; LDS dest must be wave-uniform base + lane*16
__device__ __forceinline__ void gload16(const __hip_bfloat16* g, __hip_bfloat16* l) {
    __builtin_amdgcn_global_load_lds(
        (const __attribute__((address_space(1))) unsigned int*)g,
        (__attribute__((address_space(3))) unsigned int*)l, 16, 0, 0);
}

// ---------------- dtype detect + zero counts + zero pool accum ----------------
__global__ __launch_bounds__(256) void detect_zero(const void* edge_attr,
                                                   int* flag, int* counts,
                                                   float* accum) {
    int i = blockIdx.x * 256 + threadIdx.x;
    if (i < NN) counts[i] = 0;
    if (i < DD) accum[i] = 0.0f;
    if (blockIdx.x == 0 && threadIdx.x < 64) {
        const unsigned short* p = (const unsigned short*)edge_attr;
        int nz = (p[4 * threadIdx.x] != 0) ? 1 : 0;
        unsigned long long m = __ballot(nz);
        if (threadIdx.x == 0) *flag = (__popcll(m) > 8) ? 1 : 0;
    }
}

// ---------------- input conversion ----------------

__global__ __launch_bounds__(256) void cvt_big(
    const void* x, const void* We, const int* flag,
    __hip_bfloat16* hb, __hip_bfloat16* Web) {
    long long i = (long long)blockIdx.x * 256 + threadIdx.x;
    int bf = *flag;
    const long long NX = (long long)NN * DD;
    const long long NE2 = 3LL * EDIM * DD;
    if (i < NX) { hb[i] = rd_any(x, i, bf); return; } i -= NX;
    if (i < NE2) { Web[i] = rd_any(We, i, bf); return; } i -= NE2;
    if (i < (long long)(MP - NN) * DD) hb[(long long)NN * DD + i] = __float2bfloat16(0.0f);
}

__global__ __launch_bounds__(256) void cvt_small(
    const void* ea, const void* rel, const void* Wed, const void* bed,
    const void* bk, const void* bq, const void* bv, const void* bs,
    const void* lg, const void* lb, const int* flag,
    __hip_bfloat16* eab, __hip_bfloat16* relb, __hip_bfloat16* Wedb,
    __hip_bfloat16* bedb, __hip_bfloat16* ballb, __hip_bfloat16* lgb,
    __hip_bfloat16* lbb) {
    long long i = (long long)blockIdx.x * 256 + threadIdx.x;
    int bf = *flag;
    if (i < 2LL * EE) { eab[i] = rd_any(ea, i, bf); return; } i -= 2LL * EE;
    if (i < NREL * (EDIM - 1)) { relb[i] = rd_any(rel, i, bf); return; } i -= NREL * (EDIM - 1);
    if (i < EDIM * EDIM) { Wedb[i] = rd_any(Wed, i, bf); return; } i -= EDIM * EDIM;
    if (i < EDIM) { bedb[i] = rd_any(bed, i, bf); return; } i -= EDIM;
    if (i < 3 * NB) {
        int l = (int)(i / NB), c = (int)(i % NB);
        const void* src; long long off; int outc;
        if (c < 768)       { src = bq; off = (long long)l * DD + c; outc = c; }
        else if (c < 1536) { int xx = c - 768;  src = bk;
                             off = (long long)l * DD + xx;
                             outc = 768 + (xx / 6) * 12 + xx % 6; }
        else if (c < 2304) { int xx = c - 1536; src = bv;
                             off = (long long)l * DD + xx;
                             outc = 768 + (xx / 6) * 12 + 6 + xx % 6; }
        else if (c < 3072) { src = bs; off = (long long)l * DD + (c - 2304); outc = c; }
        else { ballb[l * NB + c] = __float2bfloat16(0.0f); return; }  // Qe bias by mq_kernel
        ballb[l * NB + outc] = rd_any(src, off, bf); return;
    } i -= 3 * NB;
    if (i < DD) { lgb[i] = rd_any(lg, i, bf); return; } i -= DD;
    if (i < DD) { lbb[i] = rd_any(lb, i, bf); return; }
}

// all-layer fused transposed weights: Wt3[l][n][k].
// Column (row-of-Wt3) order: q 0..767; K/V INTERLEAVED 768..2303
// (group g: k[6g..6g+6) at 768+12g, v[6g..6g+6) at 768+12g+6); skip 2304..3071.
__global__ __launch_bounds__(256) void wt_all(
    const void* Wq, const void* Wk, const void* Wv, const void* Ws,
    const int* flag, __hip_bfloat16* Wt3) {
    __shared__ __hip_bfloat16 tile[32][33];
    int mm = blockIdx.y;            // l*4 + m
    int l = mm >> 2, m = mm & 3;
    const void* src = (m == 0) ? Wq : (m == 1) ? Wk : (m == 2) ? Wv : Ws;
    int bx = blockIdx.x;            // 24*24 tiles of 32x32
    int tr = bx / 24, tc = bx % 24;
    int k0 = tr * 32, c0 = tc * 32;
    int t = threadIdx.x;
    int rr = t >> 5, cc = t & 31;
    int bf = *flag;
    long long base = (long long)l * DD * DD;
#pragma unroll
    for (int p = 0; p < 4; p++)
        tile[p * 8 + rr][cc] =
            rd_any(src, base + (long long)(k0 + p * 8 + rr) * DD + c0 + cc, bf);
    __syncthreads();
    __hip_bfloat16* base_l = Wt3 + (size_t)l * NB * DD;
#pragma unroll
    for (int p = 0; p < 4; p++) {
        int xcol = c0 + p * 8 + rr;
        int row;
        if (m == 1)      row = 768 + (xcol / 6) * 12 + xcol % 6;
        else if (m == 2) row = 768 + (xcol / 6) * 12 + 6 + xcol % 6;
        else             row = m * 768 + xcol;       // m=0 -> q, m=3 -> skip(2304+)
        base_l[(size_t)row * DD + k0 + cc] = tile[cc][p * 8 + rr];
    }
}

// Qe-rows of Wt3: Wt3[l][3072+hj][k] = sum_c Wq[l][k][h*CC+c]*We[l][j][h*CC+c]
__global__ __launch_bounds__(256) void mq_kernel(
    const void* Wq, const void* bq, const int* flag,
    const __hip_bfloat16* __restrict__ Web, __hip_bfloat16* __restrict__ Wt3,
    __hip_bfloat16* __restrict__ ballb) {
    __shared__ float WeS[16][193];
    const int lh = blockIdx.y, l = lh >> 2, hh = lh & 3;
    const int t = threadIdx.x;
    const int bf = *flag;
    for (int i = t; i < 16 * 192; i += 256) {
        int j = i / 192, c = i % 192;
        WeS[j][c] = (float)Web[(size_t)l * EDIM * DD + (size_t)j * DD + hh * CC + c];
    }
    __syncthreads();
    const int k = blockIdx.x * 64 + (t >> 2);
    const int j0 = (t & 3) * 4;
    float s0 = 0.f, s1 = 0.f, s2 = 0.f, s3 = 0.f;
    if (bf) {
        const short8* qp = (const short8*)((const __hip_bfloat16*)Wq +
            ((size_t)l * DD + k) * DD + hh * CC);
#pragma unroll 4
        for (int ch = 0; ch < 24; ch++) {
            short8 v = qp[ch];
#pragma unroll
            for (int u = 0; u < 8; u++) {
                float w = b2f(v[u]);
                int c = ch * 8 + u;
                s0 += w * WeS[j0 + 0][c]; s1 += w * WeS[j0 + 1][c];
                s2 += w * WeS[j0 + 2][c]; s3 += w * WeS[j0 + 3][c];
            }
        }
    } else {
        const float4* qp = (const float4*)((const float*)Wq +
            ((size_t)l * DD + k) * DD + hh * CC);
#pragma unroll 4
        for (int ch = 0; ch < 48; ch++) {
            float4 v = qp[ch];
            float wv[4] = {v.x, v.y, v.z, v.w};
#pragma unroll
            for (int u = 0; u < 4; u++) {
                float w = wv[u];
                int c = ch * 4 + u;
                s0 += w * WeS[j0 + 0][c]; s1 += w * WeS[j0 + 1][c];
                s2 += w * WeS[j0 + 2][c]; s3 += w * WeS[j0 + 3][c];
            }
        }
    }
    const size_t base = (size_t)l * NB * DD;
    const int row = 3072 + hh * 16 + j0;
    Wt3[base + (size_t)(row + 0) * DD + k] = __float2bfloat16(s0);
    Wt3[base + (size_t)(row + 1) * DD + k] = __float2bfloat16(s1);
    Wt3[base + (size_t)(row + 2) * DD + k] = __float2bfloat16(s2);
    Wt3[base + (size_t)(row + 3) * DD + k] = __float2bfloat16(s3);
    if (blockIdx.x == 0 && t < 4) {
        float b0 = 0.f, b1 = 0.f, b2 = 0.f, b3 = 0.f;
        for (int c = 0; c < CC; c++) {
            float w = (float)rd_any(bq, (long long)l * DD + hh * CC + c, bf);
            b0 += w * WeS[j0 + 0][c]; b1 += w * WeS[j0 + 1][c];
            b2 += w * WeS[j0 + 2][c]; b3 += w * WeS[j0 + 3][c];
        }
        ballb[l * NB + 3072 + hh * 16 + j0 + 0] = __float2bfloat16(b0);
        ballb[l * NB + 3072 + hh * 16 + j0 + 1] = __float2bfloat16(b1);
        ballb[l * NB + 3072 + hh * 16 + j0 + 2] = __float2bfloat16(b2);
        ballb[l * NB + 3072 + hh * 16 + j0 + 3] = __float2bfloat16(b3);
    }
}

// ---------------- CSR build (incoming edges per dst) ----------------

__global__ __launch_bounds__(256) void count_kernel(const int* ei, int* counts) {
    int e = blockIdx.x * 256 + threadIdx.x;
    if (e < EE) atomicAdd(&counts[ei[EE + e]], 1);
}

// coalesced LDS scan: exclusive prefix into rowptr/cursor.
__global__ __launch_bounds__(256) void scan_kernel(const int* counts, int* rowptr,
                                                   int* cursor) {
    __shared__ int buf[NN];
    __shared__ int sdata[256];
    int t = threadIdx.x;
    for (int j = t; j < NN; j += 256) buf[j] = counts[j];
    __syncthreads();
    int base = t * 40;
    int cnt = (base < NN) ? min(40, NN - base) : 0;
    int s = 0;
    for (int i = 0; i < cnt; i++) s += buf[base + i];
    sdata[t] = s;
    __syncthreads();
    for (int off = 1; off < 256; off <<= 1) {
        int add = (t >= off) ? sdata[t - off] : 0;
        __syncthreads();
        sdata[t] += add;
        __syncthreads();
    }
    int run = sdata[t] - s;  // exclusive prefix of this chunk
    for (int i = 0; i < cnt; i++) {
        int tmp = buf[base + i];
        buf[base + i] = run;   // exclusive prefix per node
        run += tmp;
    }
    __syncthreads();
    for (int j = t; j < NN; j += 256) {
        int v = buf[j];
        cursor[j] = v;
        rowptr[j] = v;
    }
    if (t == 0) rowptr[NN] = EE;
}

__global__ __launch_bounds__(256) void fill_kernel(const int* ei, int* cursor,
                                                   int* eids, int* esrc) {
    int e = blockIdx.x * 256 + threadIdx.x;
    if (e < EE) {
        int d = ei[EE + e];
        int pos = atomicAdd(&cursor[d], 1);
        eids[pos] = e;
        esrc[pos] = ei[e];
    }
}

// ---------------- edge features (CSR-ordered, bf16) ----------------

__global__ __launch_bounds__(256) void ef_kernel(
    const int* __restrict__ eids,
    const __hip_bfloat16* __restrict__ eab, const __hip_bfloat16* __restrict__ relb,
    const __hip_bfloat16* __restrict__ Wedb, const __hip_bfloat16* __restrict__ bedb,
    __hip_bfloat16* __restrict__ efb) {
    int idx = blockIdx.x * 256 + threadIdx.x;
    if (idx >= EE * EDIM) return;
    int p = idx >> 4, j = idx & 15;
    int e = eids[p];
    int rid = (int)((float)eab[e * 2 + 0]);
    rid = min(max(rid, 0), NREL - 1);
    float w = (float)eab[e * 2 + 1];
    float s = (float)bedb[j];
#pragma unroll
    for (int i = 0; i < 15; i++)
        s += (float)relb[rid * 15 + i] * (float)Wedb[i * EDIM + j];
    s += w * (float)Wedb[15 * EDIM + j];
    efb[idx] = __float2bfloat16(s);
}

// ---------------- 256x256 4-phase GEMM + fused Qe tail blocks ----------------
// blocks 0..479:  C[NN,3072] = A[MP,768] @ Wt[3072,768]^T + bias (4-phase skew)
// blocks 480..639: Qe columns (64-wide GEMM).

__device__ __forceinline__ void stage_half(const __hip_bfloat16* g, int row0, int ktile,
                                           char* ldsdst, int tid) {
#pragma unroll
    for (int j = 0; j < 2; ++j) {
        int c = j * 512 + tid;          // linear 16B chunk index (1024 per half-tile)
        int row = c >> 3;
        int sch = (c & 7) ^ (row & 7);  // inverse-swizzled source chunk
        gload16(g + (size_t)(row0 + row) * DD + ktile * 64 + sch * 8,
                (__hip_bfloat16*)(ldsdst + c * 16));
    }
}

#define MF16(va, vb, cc) cc = __builtin_amdgcn_mfma_f32_16x16x32_bf16(va, vb, cc, 0, 0, 0)
#define BAR() __builtin_amdgcn_s_barrier()
#define WLG() asm volatile("s_waitcnt lgkmcnt(0)" ::: "memory")
#define WVM(N) asm volatile("s_waitcnt vmcnt(" #N ")" ::: "memory")
#define SB() __builtin_amdgcn_sched_barrier(0)
#define LDS8(off) (*(const short8*)(smem + (off)))

__global__ __launch_bounds__(512) void gemm256(
    const __hip_bfloat16* __restrict__ A, const __hip_bfloat16* __restrict__ Bt,
    const __hip_bfloat16* __restrict__ bias, __hip_bfloat16* __restrict__ C) {
    __shared__ __align__(16) char smem[131072];
    const int bid = (int)blockIdx.x;
    const int tid = threadIdx.x;
    const int wid = tid >> 6, lane = tid & 63;
    const int quad = lane >> 4, l15 = lane & 15;

    if (bid >= 480) {
        // ---- Qe path: 64x64 output tile, waves 0-3 compute, 4-7 idle ----
        const int m0q = (bid - 480) * 64;
        const __hip_bfloat16* Bq = Bt + (size_t)3072 * DD;
        const int xq0 = (quad ^ (l15 & 7)) * 16;
        const int xq1 = ((quad + 4) ^ (l15 & 7)) * 16;
        floatx4 qacc[4] = {};
        for (int kt = 0; kt < 12; ++kt) {
#pragma unroll
            for (int j = 0; j < 2; ++j) {
                int c = j * 512 + tid;
                int hf = c >> 9;             // 0:A, 1:B
                int cc = c & 511;
                int row = cc >> 3;
                int sch = (cc & 7) ^ (row & 7);
                const __hip_bfloat16* src = hf
                    ? (Bq + (size_t)row * DD + kt * 64 + sch * 8)
                    : (A + (size_t)(m0q + row) * DD + kt * 64 + sch * 8);
                gload16(src, (__hip_bfloat16*)(smem + c * 16));
            }
            asm volatile("s_waitcnt vmcnt(0)" ::: "memory");
            BAR();
            if (wid < 4) {
                short8 a0 = LDS8((wid * 16 + l15) * 128 + xq0);
                short8 a1 = LDS8((wid * 16 + l15) * 128 + xq1);
#pragma unroll
                for (int nt = 0; nt < 4; ++nt) {
                    short8 b0 = LDS8(8192 + (nt * 16 + l15) * 128 + xq0);
                    short8 b1 = LDS8(8192 + (nt * 16 + l15) * 128 + xq1);
                    MF16(a0, b0, qacc[nt]);
                    MF16(a1, b1, qacc[nt]);
                }
            }
            WLG();
            BAR();
        }
        if (wid < 4) {
#pragma unroll
            for (int nt = 0; nt < 4; ++nt) {
                float bb = (float)bias[3072 + nt * 16 + l15];
#pragma unroll
                for (int r = 0; r < 4; ++r) {
                    int row = m0q + wid * 16 + quad * 4 + r;
                    if (row < NN)
                        C[(size_t)row * NQ2 + 3072 + nt * 16 + l15] =
                            __float2bfloat16(qacc[nt][r] + bb);
                }
            }
        }
        return;
    }

    const int wm = wid >> 2, wn = wid & 3;          // 2M x 4N waves
    const int swz = (bid & 7) * 60 + (bid >> 3);    // bijective XCD swizzle (480=8*60)
    const int m0 = (swz / 12) * 256;
    const int n0 = (swz % 12) * 256;

    const int xa0 = (quad ^ (l15 & 7)) * 16;        // swizzled chunk offsets (bytes)
    const int xa1 = ((quad + 4) ^ (l15 & 7)) * 16;
    const int aRow = (wm * 128 + l15) * 128;        // A row base byte within slot
    const int bRow = 32768 + (wn * 64 + l15) * 128; // B row base byte within slot

    floatx4 acc[8][4] = {};
    short8 a[4][2], bA[2][2], bB[2][2];

    // prologue: kt0 {A0,A1,B0,B1} -> slot0, kt1 {B0,B1} -> slot1
    stage_half(A, m0, 0, smem + 0, tid);
    stage_half(A, m0 + 128, 0, smem + 16384, tid);
    stage_half(Bt, n0, 0, smem + 32768, tid);
    stage_half(Bt, n0 + 128, 0, smem + 49152, tid);
    stage_half(Bt, n0, 1, smem + 98304, tid);
    stage_half(Bt, n0 + 128, 1, smem + 114688, tid);
    WVM(4);
    BAR();

#pragma unroll 1
    for (int it = 0; it < 6; ++it) {
        const int kA = 2 * it + 1;                  // A halves of kt+1 -> slot1
        const int kB = (it < 5) ? 2 * it + 2 : 0;   // kt+2 -> slot0 (wrap = harmless)
        const int kC = (it < 5) ? 2 * it + 3 : 1;   // B halves of kt+3 -> slot1
        // ---- P_A0: slot0 north (m0-3 x all n); stage slot1.A(kA) ----
        stage_half(A, m0, kA, smem + 65536, tid);
        stage_half(A, m0 + 128, kA, smem + 81920, tid);
#pragma unroll
        for (int mt = 0; mt < 4; ++mt) {
            a[mt][0] = LDS8(aRow + mt * 2048 + xa0);
            a[mt][1] = LDS8(aRow + mt * 2048 + xa1);
        }
#pragma unroll
        for (int nt = 0; nt < 2; ++nt) {
            bA[nt][0] = LDS8(bRow + nt * 2048 + xa0);
            bA[nt][1] = LDS8(bRow + nt * 2048 + xa1);
            bB[nt][0] = LDS8(bRow + (nt + 2) * 2048 + xa0);
            bB[nt][1] = LDS8(bRow + (nt + 2) * 2048 + xa1);
        }
        SB(); BAR(); WLG(); SB();
        __builtin_amdgcn_s_setprio(1);
#pragma unroll
        for (int mt = 0; mt < 4; ++mt)
#pragma unroll
            for (int nt = 0; nt < 2; ++nt) {
                MF16(a[mt][0], bA[nt][0], acc[mt][nt]);
                MF16(a[mt][1], bA[nt][1], acc[mt][nt]);
                MF16(a[mt][0], bB[nt][0], acc[mt][nt + 2]);
                MF16(a[mt][1], bB[nt][1], acc[mt][nt + 2]);
            }
        __builtin_amdgcn_s_setprio(0);
        // ---- P_B0: slot0 south (m4-7); stage slot0.B(kB) ----
        stage_half(Bt, n0, kB, smem + 32768, tid);
        stage_half(Bt, n0 + 128, kB, smem + 49152, tid);
#pragma unroll
        for (int mt = 0; mt < 4; ++mt) {
            a[mt][0] = LDS8(aRow + (mt + 4) * 2048 + xa0);
            a[mt][1] = LDS8(aRow + (mt + 4) * 2048 + xa1);
        }
        WVM(4);                                     // slot1 {B(prev),A(kA)} complete
        SB(); BAR(); WLG(); SB();
        __builtin_amdgcn_s_setprio(1);
#pragma unroll
        for (int mt = 0; mt < 4; ++mt)
#pragma unroll
            for (int nt = 0; nt < 2; ++nt) {
                MF16(a[mt][0], bB[nt][0], acc[mt + 4][nt + 2]);
                MF16(a[mt][1], bB[nt][1], acc[mt + 4][nt + 2]);
                MF16(a[mt][0], bA[nt][0], acc[mt + 4][nt]);
                MF16(a[mt][1], bA[nt][1], acc[mt + 4][nt]);
            }
        __builtin_amdgcn_s_setprio(0);
        // ---- P_A1: slot1 north; stage slot0.A(kB) ----
        stage_half(A, m0, kB, smem + 0, tid);
        stage_half(A, m0 + 128, kB, smem + 16384, tid);
#pragma unroll
        for (int mt = 0; mt < 4; ++mt) {
            a[mt][0] = LDS8(65536 + aRow + mt * 2048 + xa0);
            a[mt][1] = LDS8(65536 + aRow + mt * 2048 + xa1);
        }
#pragma unroll
        for (int nt = 0; nt < 2; ++nt) {
            bA[nt][0] = LDS8(65536 + bRow + nt * 2048 + xa0);
            bA[nt][1] = LDS8(65536 + bRow + nt * 2048 + xa1);
            bB[nt][0] = LDS8(65536 + bRow + (nt + 2) * 2048 + xa0);
            bB[nt][1] = LDS8(65536 + bRow + (nt + 2) * 2048 + xa1);
        }
        SB(); BAR(); WLG(); SB();
        __builtin_amdgcn_s_setprio(1);
#pragma unroll
        for (int mt = 0; mt < 4; ++mt)
#pragma unroll
            for (int nt = 0; nt < 2; ++nt) {
                MF16(a[mt][0], bA[nt][0], acc[mt][nt]);
                MF16(a[mt][1], bA[nt][1], acc[mt][nt]);
                MF16(a[mt][0], bB[nt][0], acc[mt][nt + 2]);
                MF16(a[mt][1], bB[nt][1], acc[mt][nt + 2]);
            }
        __builtin_amdgcn_s_setprio(0);
        // ---- P_B1: slot1 south; stage slot1.B(kC) ----
        stage_half(Bt, n0, kC, smem + 98304, tid);
        stage_half(Bt, n0 + 128, kC, smem + 114688, tid);
#pragma unroll
        for (int mt = 0; mt < 4; ++mt) {
            a[mt][0] = LDS8(65536 + aRow + (mt + 4) * 2048 + xa0);
            a[mt][1] = LDS8(65536 + aRow + (mt + 4) * 2048 + xa1);
        }
        WVM(4);                                     // slot0 {B(kB),A(kB)} complete
        SB(); BAR(); WLG(); SB();
        __builtin_amdgcn_s_setprio(1);
#pragma unroll
        for (int mt = 0; mt < 4; ++mt)
#pragma unroll
            for (int nt = 0; nt < 2; ++nt) {
                MF16(a[mt][0], bB[nt][0], acc[mt + 4][nt + 2]);
                MF16(a[mt][1], bB[nt][1], acc[mt + 4][nt + 2]);
                MF16(a[mt][0], bA[nt][0], acc[mt + 4][nt]);
                MF16(a[mt][1], bA[nt][1], acc[mt + 4][nt]);
            }
        __builtin_amdgcn_s_setprio(0);
    }

    // epilogue: drain remaining stage writes, then per-wave LDS transpose-stage
    // -> coalesced 32B/lane global writes.
    asm volatile("s_waitcnt vmcnt(0)" ::: "memory");
    BAR();
    {
        short* stg = (short*)smem + wid * 1152;   // 16x68 shorts per wave, private
        float bv[4];
#pragma unroll
        for (int nt = 0; nt < 4; ++nt)
            bv[nt] = (float)bias[n0 + wn * 64 + nt * 16 + l15];
        const int rdo = (lane >> 2) * 68 + (lane & 3) * 16;
        const int grow0 = m0 + wm * 128 + (lane >> 2);
        const int gcol = n0 + wn * 64 + (lane & 3) * 16;
#pragma unroll
        for (int mt = 0; mt < 8; ++mt) {
#pragma unroll
            for (int nt = 0; nt < 4; ++nt)
#pragma unroll
                for (int r = 0; r < 4; ++r)
                    stg[(quad * 4 + r) * 68 + nt * 16 + l15] =
                        f2b(acc[mt][nt][r] + bv[nt]);
            asm volatile("s_waitcnt lgkmcnt(0)" ::: "memory");
            short8 v0 = *(const short8*)(stg + rdo);
            short8 v1 = *(const short8*)(stg + rdo + 8);
            int grow = grow0 + mt * 16;
            if (grow < NN) {
                short8* dp = (short8*)(C + (size_t)grow * NQ2 + gcol);
                dp[0] = v0; dp[1] = v1;
            }
            asm volatile("s_waitcnt lgkmcnt(0)" ::: "memory");
        }
    }
}

// ---------------- attention ----------------
// qkvs row layout (stride 3200): [q(0) | kv-interleaved(768) | skip(2304) | Qe(3072)]
// Natural node order. Lane g owns channels 6g..6g+5: K at col 768+12g, V at +6
// -> contiguous 24B read (3x short4). DEPTH-2 software pipeline: two payload
// register sets, unroll x2; load for edge p+2 issues while edge p computes.
// Edge processing order unchanged -> bitwise-identical softmax.

__global__ __launch_bounds__(256) void node_attn(
    const int* __restrict__ rowptr, const int* __restrict__ esrc,
    const __hip_bfloat16* __restrict__ qkvs, const __hip_bfloat16* __restrict__ efb,
    const __hip_bfloat16* __restrict__ Wel, __hip_bfloat16* __restrict__ hb,
    int do_gelu) {
    const int wv = threadIdx.x >> 6, lane = threadIdx.x & 63;
    const int n = blockIdx.x * 2 + (wv >> 1);   // grid = 5000 blocks, exact
    const int half = wv & 1;
    const int cb = half * 384 + lane * 6;       // channel base within 768
    const int g = half * 64 + lane;             // channel group (6 ch per group)
    const int kvoff = 768 + g * 12;             // qkvs col of this lane's K/V block
    const int sj = lane & 15;
    const int hsel = lane & 32;                 // head-group base within wave
    const float qe_gate = ((lane & 16) == 0) ? 1.0f : 0.0f;
    const int s0 = rowptr[n], s1 = rowptr[n + 1];
    const short* qk = (const short*)qkvs;
    float q[6];
    {
        const short2* qp = (const short2*)(qk + (size_t)n * NQ2 + cb);
        short2 a = qp[0], b = qp[1], c = qp[2];
        q[0] = b2f(a.x) * SCALE; q[1] = b2f(a.y) * SCALE; q[2] = b2f(b.x) * SCALE;
        q[3] = b2f(b.y) * SCALE; q[4] = b2f(c.x) * SCALE; q[5] = b2f(c.y) * SCALE;
    }
    const float qe_l = b2f(qk[(size_t)n * NQ2 + 3072 + (half * 2 + (lane >> 5)) * 16 + sj])
                       * SCALE * qe_gate;
    float m = -INFINITY, lsum = 0.f, sacc = 0.f;
    float acc[6] = {};
    // payload set 0 (even edge offsets) and set 1 (odd edge offsets)
    short4 A0 = {0,0,0,0}, B0 = {0,0,0,0}, C0 = {0,0,0,0};
    short4 A1 = {0,0,0,0}, B1 = {0,0,0,0}, C1 = {0,0,0,0};
    float e0 = 0.f, e1 = 0.f;
    if (s0 < s1) {
        const short4* kv = (const short4*)(qk + (size_t)esrc[s0] * NQ2 + kvoff);
        A0 = kv[0]; B0 = kv[1]; C0 = kv[2];
        e0 = b2f(((const short*)efb)[(size_t)s0 * 16 + sj]);
    }
    if (s0 + 1 < s1) {
        const short4* kv = (const short4*)(qk + (size_t)esrc[s0 + 1] * NQ2 + kvoff);
        A1 = kv[0]; B1 = kv[1]; C1 = kv[2];
        e1 = b2f(((const short*)efb)[(size_t)(s0 + 1) * 16 + sj]);
    }
#define ATTN_BODY(AA, BB, CC2, EF)                                            \
    do {                                                                      \
        float part = qe_l * (EF);                                             \
        part += q[0] * b2f((AA).x) + q[1] * b2f((AA).y) + q[2] * b2f((AA).z); \
        part += q[3] * b2f((AA).w) + q[4] * b2f((BB).x) + q[5] * b2f((BB).y); \
        part += __shfl_xor(part, 1); part += __shfl_xor(part, 2);             \
        part += __shfl_xor(part, 4); part += __shfl_xor(part, 8);             \
        part += __shfl_xor(part, 16);                                         \
        if (part > m + 8.0f) {                                                \
            float sc = __expf(m - part);                                      \
            m = part;                                                         \
            lsum *= sc; sacc *= sc;                                           \
            _Pragma("unroll")                                                 \
            for (int i = 0; i < 6; i++) acc[i] *= sc;                         \
        }                                                                     \
        float w = __expf(part - m);                                           \
        lsum += w;                                                            \
        sacc += w * (EF);                                                     \
        acc[0] += w * b2f((BB).z); acc[1] += w * b2f((BB).w);                 \
        acc[2] += w * b2f((CC2).x); acc[3] += w * b2f((CC2).y);               \
        acc[4] += w * b2f((CC2).z); acc[5] += w * b2f((CC2).w);               \
    } while (0)
    int p = s0;
    for (; p + 1 < s1; p += 2) {
        ATTN_BODY(A0, B0, C0, e0);
        if (p + 2 < s1) {               // refill set 0 (distance 2)
            const short4* kv = (const short4*)(qk + (size_t)esrc[p + 2] * NQ2 + kvoff);
            A0 = kv[0]; B0 = kv[1]; C0 = kv[2];
            e0 = b2f(((const short*)efb)[(size_t)(p + 2) * 16 + sj]);
        }
        ATTN_BODY(A1, B1, C1, e1);
        if (p + 3 < s1) {               // refill set 1 (distance 2)
            const short4* kv = (const short4*)(qk + (size_t)esrc[p + 3] * NQ2 + kvoff);
            A1 = kv[0]; B1 = kv[1]; C1 = kv[2];
            e1 = b2f(((const short*)efb)[(size_t)(p + 3) * 16 + sj]);
        }
    }
    if (p < s1) ATTN_BODY(A0, B0, C0, e0);   // odd tail lives in set 0
#undef ATTN_BODY
    float inv = 1.0f / (lsum + 1e-16f);
#pragma unroll
    for (int i = 0; i < 6; i++) acc[i] *= inv;
    float sS = sacc * inv;
    // skip connection
    {
        const short2* sp = (const short2*)(qk + (size_t)n * NQ2 + 2304 + cb);
        short2 a = sp[0], b = sp[1], c = sp[2];
        acc[0] += b2f(a.x); acc[1] += b2f(a.y); acc[2] += b2f(b.x);
        acc[3] += b2f(b.y); acc[4] += b2f(c.x); acc[5] += b2f(c.y);
    }
    // + S @ We (per-head 16-dim): S[h][j] broadcast via shfl from lane hsel+j
#pragma unroll
    for (int j = 0; j < 16; j++) {
        float sv = __shfl(sS, hsel + j);
        const short2* wp = (const short2*)(Wel + (size_t)j * DD + cb);
        short2 a = wp[0], b = wp[1], c = wp[2];
        acc[0] += sv * b2f(a.x); acc[1] += sv * b2f(a.y); acc[2] += sv * b2f(b.x);
        acc[3] += sv * b2f(b.y); acc[4] += sv * b2f(c.x); acc[5] += sv * b2f(c.y);
    }
    if (do_gelu) {
#pragma unroll
        for (int i = 0; i < 6; i++)
            acc[i] = 0.5f * acc[i] * (1.0f + erff(acc[i] * 0.70710678118654752f));
    }
    short2 o0, o1, o2;
    o0.x = f2b(acc[0]); o0.y = f2b(acc[1]);
    o1.x = f2b(acc[2]); o1.y = f2b(acc[3]);
    o2.x = f2b(acc[4]); o2.y = f2b(acc[5]);
    short2* hp = (short2*)(hb + (size_t)n * DD + cb);
    hp[0] = o0; hp[1] = o1; hp[2] = o2;
}

// ---------------- LN + mean pool (atomic accumulate) ----------------

__global__ __launch_bounds__(256) void ln_pool(
    const __hip_bfloat16* __restrict__ hb, const __hip_bfloat16* __restrict__ g,
    const __hip_bfloat16* __restrict__ b, float* __restrict__ accum) {
    __shared__ float sbuf[4][768];
    int grp = blockIdx.x, t = threadIdx.x;
    int wid = t >> 6, lane = t & 63;
    float gv[12], bv[12], acc[12];
#pragma unroll
    for (int i = 0; i < 12; i++) {
        gv[i] = (float)g[lane + i * 64];
        bv[i] = (float)b[lane + i * 64];
        acc[i] = 0.f;
    }
    for (int r = wid; r < 25; r += 4) {
        const __hip_bfloat16* row = hb + (size_t)(grp * 25 + r) * DD;
        float x[12];
        float s = 0.f, q = 0.f;
#pragma unroll
        for (int i = 0; i < 12; i++) {
            x[i] = (float)row[lane + i * 64];
            s += x[i]; q += x[i] * x[i];
        }
#pragma unroll
        for (int m = 32; m > 0; m >>= 1) {
            s += __shfl_xor(s, m); q += __shfl_xor(q, m);
        }
        float mu = s * (1.0f / 768.0f);
        float ms = q * (1.0f / 768.0f);
        float inv = 1.0f / sqrtf(ms - mu * mu + 1e-5f);
#pragma unroll
        for (int i = 0; i < 12; i++)
            acc[i] += (x[i] - mu) * inv * gv[i] + bv[i];
    }
#pragma unroll
    for (int i = 0; i < 12; i++) sbuf[wid][lane + i * 64] = acc[i];
    __syncthreads();
#pragma unroll
    for (int j = 0; j < 3; j++) {
        int col = t + j * 256;
        atomicAdd(&accum[col],
                  sbuf[0][col] + sbuf[1][col] + sbuf[2][col] + sbuf[3][col]);
    }
}

// final: scale accumulated column sums, store output
__global__ __launch_bounds__(256) void pool_final(
    const float* __restrict__ accum, void* __restrict__ out,
    const int* __restrict__ flag) {
    int dd = blockIdx.x * 256 + threadIdx.x;
    if (dd >= DD) return;
    float s = accum[dd] * (1.0f / 10000.0f);
    if (*flag) ((__hip_bfloat16*)out)[dd] = __float2bfloat16(s);
    else ((float*)out)[dd] = s;
}

// ---------------- launch ----------------

extern "C" void kernel_launch(void* const* d_in, const int* in_sizes, int n_in,
                              void* d_out, int out_size, void* d_ws, size_t ws_size,
                              hipStream_t stream) {
    const void* x         = d_in[0];
    const void* edge_attr = d_in[1];
    const int*  ei        = (const int*)d_in[2];
    const void* rel_emb   = d_in[3];
    const void* W_edge    = d_in[4];
    const void* b_edge    = d_in[5];
    const void* Wk        = d_in[6];
    const void* bk        = d_in[7];
    const void* Wq        = d_in[8];
    const void* bq        = d_in[9];
    const void* Wv        = d_in[10];
    const void* bv        = d_in[11];
    const void* We        = d_in[12];
    const void* Wskip     = d_in[13];
    const void* bskip     = d_in[14];
    const void* ln_g      = d_in[15];
    const void* ln_b      = d_in[16];

    char* ws = (char*)d_ws;
    // ---- workspace layout (~100.4 MB total) ----
    int*   flag    = (int*)(ws + 0);
    int*   counts  = (int*)(ws + 256);          // 40,000
    int*   rowptr  = (int*)(ws + 40448);        // 40,004
    int*   cursor  = (int*)(ws + 80640);        // 40,000
    int*   eids    = (int*)(ws + 120832);       // 400,000
    int*   esrc    = (int*)(ws + 520960);       // 400,000
    __hip_bfloat16* efb = (__hip_bfloat16*)(ws + 920960);   // 3,200,000 (CSR-ordered)
    float* accum   = (float*)(ws + 4120960);    // 3,072 (pool accumulator)
    __hip_bfloat16* eab   = (__hip_bfloat16*)(ws + 5349760);  // 400,000
    __hip_bfloat16* relb  = (__hip_bfloat16*)(ws + 5749760);  // 300
    __hip_bfloat16* Wedb  = (__hip_bfloat16*)(ws + 5750144);  // 512
    __hip_bfloat16* bedb  = (__hip_bfloat16*)(ws + 5750656);  // 32
    __hip_bfloat16* ballb = (__hip_bfloat16*)(ws + 5750784);  // 18,816 (3*NB)
    __hip_bfloat16* lngb  = (__hip_bfloat16*)(ws + 5770752);  // 1,536
    __hip_bfloat16* lnbb  = (__hip_bfloat16*)(ws + 5772288);  // 1,536
    __hip_bfloat16* Web   = (__hip_bfloat16*)(ws + 5773824);  // 73,728
    __hip_bfloat16* hb    = (__hip_bfloat16*)(ws + 5847552);  // 15,728,640 (MP*768)
    __hip_bfloat16* Wt3   = (__hip_bfloat16*)(ws + 21576192); // 14,450,688 (3*NB*768)
    __hip_bfloat16* qkvs  = (__hip_bfloat16*)(ws + 36911616); // 64,000,000 -> 100,911,616

    dim3 blk(256);

    detect_zero<<<dim3(40), blk, 0, stream>>>(edge_attr, flag, counts, accum);

    {
        long long tot = (long long)NN * DD + 3LL * EDIM * DD + (long long)(MP - NN) * DD;
        cvt_big<<<dim3((unsigned)((tot + 255) / 256)), blk, 0, stream>>>(x, We, flag, hb, Web);
    }
    {
        long long tot = 2LL * EE + NREL * (EDIM - 1) + EDIM * EDIM + EDIM
                        + 3LL * NB + 2LL * DD;
        cvt_small<<<dim3((unsigned)((tot + 255) / 256)), blk, 0, stream>>>(
            edge_attr, rel_emb, W_edge, b_edge, bk, bq, bv, bskip, ln_g, ln_b,
            flag, eab, relb, Wedb, bedb, ballb, lngb, lnbb);
    }
    wt_all<<<dim3(576, 12), blk, 0, stream>>>(Wq, Wk, Wv, Wskip, flag, Wt3);
    mq_kernel<<<dim3(12, 12), blk, 0, stream>>>(Wq, bq, flag, Web, Wt3, ballb);

    // CSR build
    count_kernel<<<dim3((EE + 255) / 256), blk, 0, stream>>>(ei, counts);
    scan_kernel<<<dim3(1), blk, 0, stream>>>(counts, rowptr, cursor);
    fill_kernel<<<dim3((EE + 255) / 256), blk, 0, stream>>>(ei, cursor, eids, esrc);

    ef_kernel<<<dim3((EE * EDIM) / 256), blk, 0, stream>>>(eids, eab, relb, Wedb, bedb, efb);

    for (int l = 0; l < 3; l++) {
        const __hip_bfloat16* We_l = Web + (size_t)l * EDIM * DD;
        gemm256<<<dim3(640), dim3(512), 0, stream>>>(
            hb, Wt3 + (size_t)l * NB * DD, ballb + (size_t)l * NB, qkvs);
        node_attn<<<dim3(NN / 2), blk, 0, stream>>>(rowptr, esrc, qkvs, efb,
                                                    We_l, hb, (l < 2) ? 1 : 0);
    }

    ln_pool<<<dim3(400), blk, 0, stream>>>(hb, lngb, lnbb, accum);
    pool_final<<<dim3(3), blk, 0, stream>>>(accum, d_out, flag);
}